// Round 1
// 345.825 us; speedup vs baseline: 1.0134x; 1.0134x over previous
//
#include <hip/hip_runtime.h>
#include <math.h>

// ---------------------------------------------------------------------------
// GraphSAGE fraud detector. CSR-gather aggregation + bf16 MFMA GEMMs.
// R17: layer-2 GEMM ported to the 256x256 8-phase schedule (T2 st_16x32
// LDS swizzle + T3/T4 counted-vmcnt phases + T5 setprio), per the m201
// template. Layer-1 stays on the R12/R14 128^2 kernel (K=256, small).
// Stage stream (shifted 1 phase vs guide; vmcnt(4) gates, provably safe):
//   p0:Ah0(t1) p1:Ah1(t1) p2:Bh0(t2) p3:Bh1(t2)+GATE p4:Ah0(t2) p5:Ah1(t2)
//   p6:Bh0(t3) p7:Bh1(t3)+GATE   (t0=2j,t1=2j+1 computed; t2,t3 prefetched)
// Every overwrite lands >=2 barriers after the last read of its slot; every
// K-tile is vmcnt-gated >=1 phase before its first ds_read.
// MFMA 16x16x32 bf16: A-frag A[m=lane&15][k=quad*8+j]; C/D col=lane&15,
// row=quad*4+reg (m89/m97-verified layouts).
// ---------------------------------------------------------------------------

typedef __attribute__((ext_vector_type(8))) short bf16x8;   // 8 bf16, 4 VGPRs
typedef __attribute__((ext_vector_type(4))) float f32x4;

static inline int ceil_div(int a, int b) { return (a + b - 1) / b; }

__device__ inline float bf2f_lo(unsigned u) { return __builtin_bit_cast(float, u << 16); }
__device__ inline float bf2f_hi(unsigned u) { return __builtin_bit_cast(float, u & 0xffff0000u); }
__device__ inline unsigned f2bf(float f) {   // RNE round to bf16, bits in low 16
    unsigned u = __builtin_bit_cast(unsigned, f);
    u += 0x7fffu + ((u >> 16) & 1u);
    return u >> 16;
}

// async global->LDS, 16 B per lane; LDS dest = wave-uniform base + lane*16
#define GLOAD_LDS16(gp, lp)                                                   \
    __builtin_amdgcn_global_load_lds(                                         \
        (__attribute__((address_space(1))) void*)(gp),                        \
        (__attribute__((address_space(3))) void*)(lp), 16, 0, 0)

// ---------------- fused cvt(x,W1,W2) + deg histogram ----------------

__global__ void cvt3_hist_kernel(const float* __restrict__ a, unsigned short* __restrict__ ao, int na4,
                                 const float* __restrict__ b, unsigned short* __restrict__ bo, int nb4,
                                 const float* __restrict__ c, unsigned short* __restrict__ co, int nc4,
                                 const int* __restrict__ dst, int* __restrict__ deg, int E,
                                 int cvt_blocks) {
    if ((int)blockIdx.x < cvt_blocks) {
        int i = blockIdx.x * 256 + threadIdx.x;
        const float* in; unsigned short* out; int k;
        if (i < na4)                  { in = a; out = ao; k = i; }
        else if (i < na4 + nb4)       { in = b; out = bo; k = i - na4; }
        else if (i < na4 + nb4 + nc4) { in = c; out = co; k = i - na4 - nb4; }
        else return;
        float4 v = ((const float4*)in)[k];
        ushort4 o;
        o.x = (unsigned short)f2bf(v.x);
        o.y = (unsigned short)f2bf(v.y);
        o.z = (unsigned short)f2bf(v.z);
        o.w = (unsigned short)f2bf(v.w);
        ((ushort4*)out)[k] = o;
    } else {
        int e = (blockIdx.x - cvt_blocks) * 256 + threadIdx.x;
        if (e < E) atomicAdd(&deg[dst[e]], 1);
    }
}

// ---------------- CSR build ----------------

// per-1024-chunk sums
__global__ __launch_bounds__(256) void chunk_reduce(const int* __restrict__ deg,
                                                    int* __restrict__ partial, int N) {
    int base = blockIdx.x * 1024;
    int s = 0;
    for (int i = threadIdx.x; i < 1024; i += 256) {
        int idx = base + i;
        if (idx < N) s += deg[idx];
    }
    #pragma unroll
    for (int off = 32; off; off >>= 1) s += __shfl_down(s, off);
    __shared__ int ws[4];
    if ((threadIdx.x & 63) == 0) ws[threadIdx.x >> 6] = s;
    __syncthreads();
    if (threadIdx.x == 0) partial[blockIdx.x] = ws[0] + ws[1] + ws[2] + ws[3];
}

// exclusive scan of P<=64 partials (one wave); writes rowstart[N]=total
__global__ void partial_scan(int* __restrict__ partial, int* __restrict__ rowstartN, int P) {
    int lane = threadIdx.x;
    int v = (lane < P) ? partial[lane] : 0;
    int incl = v;
    #pragma unroll
    for (int off = 1; off < 64; off <<= 1) {
        int t = __shfl_up(incl, off);
        if (lane >= off) incl += t;
    }
    if (lane < P) partial[lane] = incl - v;
    if (lane == 63) *rowstartN = incl;
}

// per-chunk exclusive scan + global offset; writes rowstart and cursor
__global__ __launch_bounds__(256) void chunk_scan(const int* __restrict__ deg,
                                                  const int* __restrict__ partial,
                                                  int* __restrict__ rowstart,
                                                  int* __restrict__ cursor, int N) {
    int base = blockIdx.x * 1024 + threadIdx.x * 4;
    int v[4];
    #pragma unroll
    for (int j = 0; j < 4; ++j) {
        int i = base + j;
        v[j] = (i < N) ? deg[i] : 0;
    }
    int mysum = v[0] + v[1] + v[2] + v[3];
    int incl = mysum;
    int lane = threadIdx.x & 63, wave = threadIdx.x >> 6;
    #pragma unroll
    for (int off = 1; off < 64; off <<= 1) {
        int t = __shfl_up(incl, off);
        if (lane >= off) incl += t;
    }
    __shared__ int ws[4];
    if (lane == 63) ws[wave] = incl;
    __syncthreads();
    int run = partial[blockIdx.x] + incl - mysum;
    for (int w = 0; w < wave; ++w) run += ws[w];
    #pragma unroll
    for (int j = 0; j < 4; ++j) {
        int i = base + j;
        if (i < N) { rowstart[i] = run; cursor[i] = run; }
        run += v[j];
    }
}

__global__ void bucket_kernel(const int* __restrict__ src, const int* __restrict__ dst,
                              int* __restrict__ cursor, int* __restrict__ ebuf, int E) {
    int e = blockIdx.x * 256 + threadIdx.x;
    if (e < E) {
        int pos = atomicAdd(&cursor[dst[e]], 1);
        ebuf[pos] = src[e];
    }
}

// ---------------- gather means ----------------

// one wave per dst row; bf16 xb [N,128] -> bf16 mean [N,128]; fp32 accum
__global__ void gather_mean_128(const int* __restrict__ rowstart, const int* __restrict__ ebuf,
                                const unsigned* __restrict__ featb, unsigned* __restrict__ outb, int N) {
    int w = (blockIdx.x * blockDim.x + threadIdx.x) >> 6;
    int lane = threadIdx.x & 63;
    if (w >= N) return;
    int e0 = rowstart[w], e1 = rowstart[w + 1];
    float ax = 0.0f, ay = 0.0f;
    int i = e0;
    for (; i + 8 <= e1; i += 8) {           // 8-edge unroll for MLP
        unsigned v0 = featb[(size_t)ebuf[i]     * 64 + lane];
        unsigned v1 = featb[(size_t)ebuf[i + 1] * 64 + lane];
        unsigned v2 = featb[(size_t)ebuf[i + 2] * 64 + lane];
        unsigned v3 = featb[(size_t)ebuf[i + 3] * 64 + lane];
        unsigned v4 = featb[(size_t)ebuf[i + 4] * 64 + lane];
        unsigned v5 = featb[(size_t)ebuf[i + 5] * 64 + lane];
        unsigned v6 = featb[(size_t)ebuf[i + 6] * 64 + lane];
        unsigned v7 = featb[(size_t)ebuf[i + 7] * 64 + lane];
        ax += bf2f_lo(v0) + bf2f_lo(v1) + bf2f_lo(v2) + bf2f_lo(v3)
            + bf2f_lo(v4) + bf2f_lo(v5) + bf2f_lo(v6) + bf2f_lo(v7);
        ay += bf2f_hi(v0) + bf2f_hi(v1) + bf2f_hi(v2) + bf2f_hi(v3)
            + bf2f_hi(v4) + bf2f_hi(v5) + bf2f_hi(v6) + bf2f_hi(v7);
    }
    for (; i < e1; ++i) {
        unsigned v = featb[(size_t)ebuf[i] * 64 + lane];
        ax += bf2f_lo(v); ay += bf2f_hi(v);
    }
    float inv = 1.0f / fmaxf((float)(e1 - e0), 1.0f);
    outb[(size_t)w * 64 + lane] = f2bf(ax * inv) | (f2bf(ay * inv) << 16);
}

// one wave per dst row; bf16 feat [N,512] -> bf16 mean [N,512]; fp32 accum
__global__ void gather_mean_512(const int* __restrict__ rowstart, const int* __restrict__ ebuf,
                                const unsigned short* __restrict__ featb,
                                unsigned short* __restrict__ outb, int N) {
    int w = (blockIdx.x * blockDim.x + threadIdx.x) >> 6;
    int lane = threadIdx.x & 63;
    if (w >= N) return;
    int e0 = rowstart[w], e1 = rowstart[w + 1];
    float a[8] = {0, 0, 0, 0, 0, 0, 0, 0};
    const uint4* base = (const uint4*)featb;     // 512 bf16/row = 64 uint4/row
    int i = e0;
    for (; i + 8 <= e1; i += 8) {           // 8-edge unroll for MLP
        uint4 v0 = base[(size_t)ebuf[i]     * 64 + lane];
        uint4 v1 = base[(size_t)ebuf[i + 1] * 64 + lane];
        uint4 v2 = base[(size_t)ebuf[i + 2] * 64 + lane];
        uint4 v3 = base[(size_t)ebuf[i + 3] * 64 + lane];
        uint4 v4 = base[(size_t)ebuf[i + 4] * 64 + lane];
        uint4 v5 = base[(size_t)ebuf[i + 5] * 64 + lane];
        uint4 v6 = base[(size_t)ebuf[i + 6] * 64 + lane];
        uint4 v7 = base[(size_t)ebuf[i + 7] * 64 + lane];
        a[0] += bf2f_lo(v0.x) + bf2f_lo(v1.x) + bf2f_lo(v2.x) + bf2f_lo(v3.x)
              + bf2f_lo(v4.x) + bf2f_lo(v5.x) + bf2f_lo(v6.x) + bf2f_lo(v7.x);
        a[1] += bf2f_hi(v0.x) + bf2f_hi(v1.x) + bf2f_hi(v2.x) + bf2f_hi(v3.x)
              + bf2f_hi(v4.x) + bf2f_hi(v5.x) + bf2f_hi(v6.x) + bf2f_hi(v7.x);
        a[2] += bf2f_lo(v0.y) + bf2f_lo(v1.y) + bf2f_lo(v2.y) + bf2f_lo(v3.y)
              + bf2f_lo(v4.y) + bf2f_lo(v5.y) + bf2f_lo(v6.y) + bf2f_lo(v7.y);
        a[3] += bf2f_hi(v0.y) + bf2f_hi(v1.y) + bf2f_hi(v2.y) + bf2f_hi(v3.y)
              + bf2f_hi(v4.y) + bf2f_hi(v5.y) + bf2f_hi(v6.y) + bf2f_hi(v7.y);
        a[4] += bf2f_lo(v0.z) + bf2f_lo(v1.z) + bf2f_lo(v2.z) + bf2f_lo(v3.z)
              + bf2f_lo(v4.z) + bf2f_lo(v5.z) + bf2f_lo(v6.z) + bf2f_lo(v7.z);
        a[5] += bf2f_hi(v0.z) + bf2f_hi(v1.z) + bf2f_hi(v2.z) + bf2f_hi(v3.z)
              + bf2f_hi(v4.z) + bf2f_hi(v5.z) + bf2f_hi(v6.z) + bf2f_hi(v7.z);
        a[6] += bf2f_lo(v0.w) + bf2f_lo(v1.w) + bf2f_lo(v2.w) + bf2f_lo(v3.w)
              + bf2f_lo(v4.w) + bf2f_lo(v5.w) + bf2f_lo(v6.w) + bf2f_lo(v7.w);
        a[7] += bf2f_hi(v0.w) + bf2f_hi(v1.w) + bf2f_hi(v2.w) + bf2f_hi(v3.w)
              + bf2f_hi(v4.w) + bf2f_hi(v5.w) + bf2f_hi(v6.w) + bf2f_hi(v7.w);
    }
    for (; i < e1; ++i) {
        uint4 v = base[(size_t)ebuf[i] * 64 + lane];
        a[0] += bf2f_lo(v.x); a[1] += bf2f_hi(v.x);
        a[2] += bf2f_lo(v.y); a[3] += bf2f_hi(v.y);
        a[4] += bf2f_lo(v.z); a[5] += bf2f_hi(v.z);
        a[6] += bf2f_lo(v.w); a[7] += bf2f_hi(v.w);
    }
    float inv = 1.0f / fmaxf((float)(e1 - e0), 1.0f);
    uint4 o;
    o.x = f2bf(a[0] * inv) | (f2bf(a[1] * inv) << 16);
    o.y = f2bf(a[2] * inv) | (f2bf(a[3] * inv) << 16);
    o.z = f2bf(a[4] * inv) | (f2bf(a[5] * inv) << 16);
    o.w = f2bf(a[6] * inv) | (f2bf(a[7] * inv) << 16);
    ((uint4*)outb)[(size_t)w * 64 + lane] = o;
}

// ---------------- bf16 MFMA GEMM (R12-exact: BK=32, XCD swizzle) -----------
// Retained for layer 1 (K=256). See R16 comment history.
__global__ __launch_bounds__(256) void gemm_mfma(
    const unsigned short* __restrict__ A0,   // [N, K0] bf16
    const unsigned short* __restrict__ A1,   // [N, K1] bf16, K1 == K0
    const unsigned short* __restrict__ W,    // [C, K0+K1] bf16 row-major
    const float* __restrict__ b,             // [C] fp32
    unsigned short* __restrict__ outb,       // [N, C] bf16 (mode 0)
    const float* __restrict__ Wo,            // [C] fp32    (mode 1)
    float* __restrict__ logit,               // [N] fp32    (mode 1)
    int N, int K0, int K1, int C, int mode)
{
    // --- XCD-aware decode ---
    const int nrow = (N + 127) >> 7;
    const int id   = blockIdx.x;
    const int rowb = ((id >> 5) << 3) + (id & 7);   // rslot*8 + xcd
    const int colb = (id >> 3) & 3;
    if (rowb >= nrow) return;

    const int K = K0 + K1;
    const int S = K0;               // row stride of both A0 and A1
    __shared__ short As[2][4096];   // [128][32] per buffer, 8 KB
    __shared__ short Bs[2][4096];

    const int tid  = threadIdx.x;
    const int lane = tid & 63;
    const int wave = tid >> 6;
    const int wm = wave & 1, wn = wave >> 1;
    const int cl = lane & 15, quad = lane >> 4;
    const int row0 = rowb * 128;
    const int col0 = colb * 128;

    // staging: lane = 4r+j; wave w, load i covers tile rows w*32+i*16 .. +16
    const int r = lane >> 2;        // 0..15
    const int j = lane & 3;         // 16B chunk within the row's 64B K-slice
    const int trow0 = wave * 32 + r;
    const int trow1 = trow0 + 16;
    // clamp OOB tile rows to N-1 (loaded garbage discarded by epilogue guard)
    const int ar0 = (row0 + trow0 < N) ? row0 + trow0 : N - 1;
    const int ar1 = (row0 + trow1 < N) ? row0 + trow1 : N - 1;
    const size_t aoff0 = (size_t)ar0 * S + j * 8;
    const size_t aoff1 = (size_t)ar1 * S + j * 8;
    const size_t boff0 = (size_t)(col0 + trow0) * K + j * 8;
    const size_t boff1 = (size_t)(col0 + trow1) * K + j * 8;
    const int lds0 = (wave * 32) * 32;        // shorts; wave-uniform
    const int lds1 = (wave * 32 + 16) * 32;

    f32x4 acc[4][4];
    #pragma unroll
    for (int mt = 0; mt < 4; ++mt)
        #pragma unroll
        for (int nt = 0; nt < 4; ++nt)
            acc[mt][nt] = (f32x4){0.f, 0.f, 0.f, 0.f};

    // prologue: DMA tile 0 into buffer 0
    GLOAD_LDS16(A0 + aoff0, &As[0][lds0]);
    GLOAD_LDS16(A0 + aoff1, &As[0][lds1]);
    GLOAD_LDS16(W  + boff0, &Bs[0][lds0]);
    GLOAD_LDS16(W  + boff1, &Bs[0][lds1]);

    const int iters = K >> 5;
    for (int i = 0; i < iters; ++i) {
        const int cur = i & 1;
        // barrier drains tile i's DMA (vmcnt0) and fences tile i-1 frag reads
        __syncthreads();
        if (i + 1 < iters) {
            const int kn = (i + 1) << 5;
            const unsigned short* Ab = (kn < K0) ? (A0 + kn) : (A1 + (kn - K0));
            const unsigned short* Wb = W + kn;
            const int nb = cur ^ 1;
            GLOAD_LDS16(Ab + aoff0, &As[nb][lds0]);
            GLOAD_LDS16(Ab + aoff1, &As[nb][lds1]);
            GLOAD_LDS16(Wb + boff0, &Bs[nb][lds0]);
            GLOAD_LDS16(Wb + boff1, &Bs[nb][lds1]);
        }

        bf16x8 af[4], bfr[4];
        #pragma unroll
        for (int mt = 0; mt < 4; ++mt)
            af[mt] = *(const bf16x8*)&As[cur][(wm * 64 + mt * 16 + cl) * 32 + quad * 8];
        #pragma unroll
        for (int nt = 0; nt < 4; ++nt)
            bfr[nt] = *(const bf16x8*)&Bs[cur][(wn * 64 + nt * 16 + cl) * 32 + quad * 8];

        #pragma unroll
        for (int mt = 0; mt < 4; ++mt)
            #pragma unroll
            for (int nt = 0; nt < 4; ++nt)
                acc[mt][nt] = __builtin_amdgcn_mfma_f32_16x16x32_bf16(
                    af[mt], bfr[nt], acc[mt][nt], 0, 0, 0);
    }

    if (mode == 0) {
        #pragma unroll
        for (int nt = 0; nt < 4; ++nt) {
            const int colx = col0 + wn * 64 + nt * 16 + cl;
            const float bb = b[colx];
            #pragma unroll
            for (int mt = 0; mt < 4; ++mt) {
                #pragma unroll
                for (int rr = 0; rr < 4; ++rr) {
                    int row = row0 + wm * 64 + mt * 16 + quad * 4 + rr;
                    if (row < N)
                        outb[(size_t)row * C + colx] =
                            (unsigned short)f2bf(fmaxf(acc[mt][nt][rr] + bb, 0.0f));
                }
            }
        }
    } else {
        float bv[4], wv2[4];
        #pragma unroll
        for (int nt = 0; nt < 4; ++nt) {
            const int colx = col0 + wn * 64 + nt * 16 + cl;
            bv[nt] = b[colx];
            wv2[nt] = Wo[colx];
        }
        #pragma unroll
        for (int mt = 0; mt < 4; ++mt) {
            #pragma unroll
            for (int rr = 0; rr < 4; ++rr) {
                float s = 0.0f;
                #pragma unroll
                for (int nt = 0; nt < 4; ++nt)
                    s += fmaxf(acc[mt][nt][rr] + bv[nt], 0.0f) * wv2[nt];
                s += __shfl_xor(s, 1);
                s += __shfl_xor(s, 2);
                s += __shfl_xor(s, 4);
                s += __shfl_xor(s, 8);
                int row = row0 + wm * 64 + mt * 16 + quad * 4 + rr;
                if (cl == 0 && row < N) atomicAdd(&logit[row], s);
            }
        }
    }
}

// ---------------- layer-2: 256x256-tile 8-phase GEMM + fused head ----------
// C = relu([A0|A1] @ W^T + b); logit[row] += sum_col C[row,col]*Wo[col].
// Fixed shape: A row stride 512 (K0=K1=512, K=1024), W [512][1024].
// 512 thr = 8 waves (2Mx4N); wave tile 128x64; BK=64; 2 K-tiles per iter,
// 8 phases per iter, 16 MFMA per phase. LDS 128 KiB (2 dbuf x (A 32K + B 32K)).
// T2 swizzle: logical byte ^ ((bit9)<<5); linear LDS dest (global_load_lds),
// inverse-swizzled GLOBAL source, swizzled ds_read (rule 21 both-sides).
// Counted vmcnt(4) gates at p3/p7; one lgkmcnt(0) per phase; setprio on MFMA.

#define KT2  16   // K-tiles of 64 (K = 1024)
#define NIT2 8    // iterations (2 K-tiles each)

#define STG_A(hh, kt, buf) do {                                                        \
    const unsigned short* _pA = ((kt) < 8) ? A0 : A1;                                  \
    const size_t _ko = (size_t)(((kt) & 7) << 6);                                      \
    GLOAD_LDS16(_pA + _ko + offA[hh][0],                                               \
                lds + (buf) * 65536 + (hh) * 16384 + (w * 2 + 0) * 1024);              \
    GLOAD_LDS16(_pA + _ko + offA[hh][1],                                               \
                lds + (buf) * 65536 + (hh) * 16384 + (w * 2 + 1) * 1024);              \
} while (0)

#define STG_B(hh, kt, buf) do {                                                        \
    const size_t _ko = (size_t)((kt) << 6);                                            \
    GLOAD_LDS16(W + _ko + offB[hh][0],                                                 \
                lds + (buf) * 65536 + 32768 + (hh) * 16384 + (w * 2 + 0) * 1024);      \
    GLOAD_LDS16(W + _ko + offB[hh][1],                                                 \
                lds + (buf) * 65536 + 32768 + (hh) * 16384 + (w * 2 + 1) * 1024);      \
} while (0)

#define RD_A8(qm, buf) do {                                                            \
    _Pragma("unroll")                                                                  \
    for (int _m = 0; _m < 4; ++_m) {                                                   \
        af[_m][0] = *(const bf16x8*)(lds + (buf) * 65536 +                             \
                    ((aBase + ((qm) * 4 + _m) * 2048) ^ swz));                         \
        af[_m][1] = *(const bf16x8*)(lds + (buf) * 65536 +                             \
                    ((aBase + ((qm) * 4 + _m) * 2048 + 64) ^ swz));                    \
    }                                                                                  \
} while (0)

#define RD_B4(qn, buf) do {                                                            \
    _Pragma("unroll")                                                                  \
    for (int _n = 0; _n < 2; ++_n) {                                                   \
        bq[(qn) * 2 + _n][0] = *(const bf16x8*)(lds + (buf) * 65536 +                  \
                    ((bBase + ((qn) * 2 + _n) * 2048) ^ swz));                         \
        bq[(qn) * 2 + _n][1] = *(const bf16x8*)(lds + (buf) * 65536 +                  \
                    ((bBase + ((qn) * 2 + _n) * 2048 + 64) ^ swz));                    \
    }                                                                                  \
} while (0)

#define MFMA16(qm, qn) do {                                                            \
    _Pragma("unroll")                                                                  \
    for (int _kk = 0; _kk < 2; ++_kk)                                                  \
        _Pragma("unroll")                                                              \
        for (int _m = 0; _m < 4; ++_m)                                                 \
            _Pragma("unroll")                                                          \
            for (int _n = 0; _n < 2; ++_n)                                             \
                acc[(qm) * 4 + _m][(qn) * 2 + _n] =                                    \
                    __builtin_amdgcn_mfma_f32_16x16x32_bf16(                           \
                        af[_m][_kk], bq[(qn) * 2 + _n][_kk],                           \
                        acc[(qm) * 4 + _m][(qn) * 2 + _n], 0, 0, 0);                   \
} while (0)

#define PH_SYNC_MFMA(qm, qn) do {                                                      \
    __builtin_amdgcn_sched_barrier(0);                                                 \
    __builtin_amdgcn_s_barrier();                                                      \
    __builtin_amdgcn_sched_barrier(0);                                                 \
    asm volatile("s_waitcnt lgkmcnt(0)" ::: "memory");                                 \
    __builtin_amdgcn_s_setprio(1);                                                     \
    MFMA16(qm, qn);                                                                    \
    __builtin_amdgcn_s_setprio(0);                                                     \
    __builtin_amdgcn_sched_barrier(0);                                                 \
    __builtin_amdgcn_s_barrier();                                                      \
    __builtin_amdgcn_sched_barrier(0);                                                 \
} while (0)

__global__ __launch_bounds__(512, 2) void gemm2_8ph(
    const unsigned short* __restrict__ A0,   // h1b [N,512] bf16
    const unsigned short* __restrict__ A1,   // n2b [N,512] bf16
    const unsigned short* __restrict__ W,    // W2b [512,1024] bf16
    const float* __restrict__ b,             // b2 [512]
    const float* __restrict__ Wo,            // [512]
    float* __restrict__ logit,               // [N]
    int N)
{
    __shared__ char lds[131072];             // 2 dbuf x (A 32K | B 32K)

    // XCD-aware swizzle: col siblings of a row-tile on one XCD (A L2-reuse)
    const int nrt = (N + 255) >> 8;
    const int nb  = nrt * 2;
    const int orig = blockIdx.x;
    int virt = orig;
    if ((nb & 7) == 0) virt = (orig & 7) * (nb >> 3) + (orig >> 3);
    const int row0 = (virt >> 1) << 8;
    const int col0 = (virt & 1) << 8;

    const int tid = threadIdx.x;
    const int w = tid >> 6, l = tid & 63;
    const int wr = w >> 2, wc = w & 3;       // 2x4 wave grid
    const int cl = l & 15, quad = l >> 4;

    // ---- staging addresses (inverse-swizzled global source; linear dest) ----
    // dest byte t = hh*16384 + (w*2+i)*1024 + l*16  ->  logical row = t>>7,
    // col = (l&7)*8 ^ ((l>>5)<<4)  (bit9 of t = l>>5; involution on bit5)
    const int c_log = ((l & 7) * 8) ^ ((l >> 5) << 4);
    size_t offA[2][2], offB[2][2];
    #pragma unroll
    for (int hh = 0; hh < 2; ++hh)
        #pragma unroll
        for (int i = 0; i < 2; ++i) {
            int ra = row0 + hh * 128 + (w * 2 + i) * 8 + (l >> 3);
            if (ra > N - 1) ra = N - 1;      // clamp; epilogue guards row<N
            offA[hh][i] = (size_t)ra * 512 + c_log;
            const int rb = col0 + hh * 128 + (w * 2 + i) * 8 + (l >> 3);
            offB[hh][i] = (size_t)rb * 1024 + c_log;
        }

    // ---- ds_read bases: logical byte ^ swz, swz = bit9(logical)<<5 = (cl&4)<<3
    const int swz   = (cl & 4) << 3;
    const int aBase = wr * 16384 + cl * 128 + quad * 16;           // + mt*2048 + kk*64
    const int bBase = 32768 + (wc * 64 + cl) * 128 + quad * 16;    // + nt*2048 + kk*64

    f32x4 acc[8][4];
    #pragma unroll
    for (int mt = 0; mt < 8; ++mt)
        #pragma unroll
        for (int nt = 0; nt < 4; ++nt)
            acc[mt][nt] = (f32x4){0.f, 0.f, 0.f, 0.f};

    bf16x8 af[4][2];     // A frags of current qm group
    bf16x8 bq[4][2];     // all B frags of current K-tile

    // ---- prologue: t0 fully (8 instr), then B(t1) (4 instr) ----
    STG_A(0, 0, 0); STG_A(1, 0, 0);
    STG_B(0, 0, 0); STG_B(1, 0, 0);
    STG_B(0, 1, 1); STG_B(1, 1, 1);
    asm volatile("s_waitcnt vmcnt(4)" ::: "memory");   // t0 landed; B(t1) may fly
    __builtin_amdgcn_s_barrier();
    __builtin_amdgcn_sched_barrier(0);

    for (int j = 0; j < NIT2; ++j) {
        const int t1 = 2 * j + 1;
        const int t2 = (2 * j + 2 < KT2) ? 2 * j + 2 : KT2 - 2;  // clamped, even
        const int t3 = (2 * j + 3 < KT2) ? 2 * j + 3 : KT2 - 1;  // clamped, odd
        // ---- K-tile t0 = 2j (buf0) ----
        RD_A8(0, 0); RD_B4(0, 0);                 // 12 ds_reads
        STG_A(0, t1, 1);                          // overwrites A(t1-2), last read prev p6
        asm volatile("s_waitcnt lgkmcnt(8)" ::: "memory");
        PH_SYNC_MFMA(0, 0);                       // p0
        RD_B4(1, 0);
        STG_A(1, t1, 1);
        PH_SYNC_MFMA(0, 1);                       // p1
        RD_A8(1, 0);
        STG_B(0, t2, 0);                          // overwrites B(t0), last read p1
        PH_SYNC_MFMA(1, 1);                       // p2
        STG_B(1, t2, 0);
        asm volatile("s_waitcnt vmcnt(4)" ::: "memory");   // GATE t1: A@p0,p1 landed
        PH_SYNC_MFMA(1, 0);                       // p3
        // ---- K-tile t1 = 2j+1 (buf1) ----
        RD_A8(0, 1); RD_B4(0, 1);
        STG_A(0, t2, 0);                          // overwrites A(t0), last read p2
        asm volatile("s_waitcnt lgkmcnt(8)" ::: "memory");
        PH_SYNC_MFMA(0, 0);                       // p4
        RD_B4(1, 1);
        STG_A(1, t2, 0);
        PH_SYNC_MFMA(0, 1);                       // p5
        RD_A8(1, 1);
        STG_B(0, t3, 1);                          // overwrites B(t1), last read p5
        PH_SYNC_MFMA(1, 1);                       // p6
        STG_B(1, t3, 1);
        asm volatile("s_waitcnt vmcnt(4)" ::: "memory");   // GATE t2: B@p2,p3 A@p4,p5
        PH_SYNC_MFMA(1, 0);                       // p7
    }
    asm volatile("s_waitcnt vmcnt(0)" ::: "memory");   // drain tail stages

    // ---- epilogue: fused ReLU + Wo dot + atomic row add ----
    float bv[4], wv[4];
    #pragma unroll
    for (int nt = 0; nt < 4; ++nt) {
        const int colx = col0 + wc * 64 + nt * 16 + cl;
        bv[nt] = b[colx];
        wv[nt] = Wo[colx];
    }
    #pragma unroll
    for (int mt = 0; mt < 8; ++mt) {
        #pragma unroll
        for (int rr = 0; rr < 4; ++rr) {
            float s = 0.0f;
            #pragma unroll
            for (int nt = 0; nt < 4; ++nt)
                s += fmaxf(acc[mt][nt][rr] + bv[nt], 0.0f) * wv[nt];
            s += __shfl_xor(s, 1);
            s += __shfl_xor(s, 2);
            s += __shfl_xor(s, 4);
            s += __shfl_xor(s, 8);
            const int row = row0 + wr * 128 + mt * 16 + quad * 4 + rr;
            if (cl == 0 && row < N) atomicAdd(&logit[row], s);
        }
    }
}

__global__ void head_kernel(const float* __restrict__ logit, const float* __restrict__ bo,
                            float* __restrict__ out, int N) {
    int i = blockIdx.x * 256 + threadIdx.x;
    if (i < N) out[i] = 1.0f / (1.0f + expf(-(logit[i] + bo[0])));
}

extern "C" void kernel_launch(void* const* d_in, const int* in_sizes, int n_in,
                              void* d_out, int out_size, void* d_ws, size_t ws_size,
                              hipStream_t stream) {
    const float* x  = (const float*)d_in[0];
    const int*   ei = (const int*)d_in[1];
    const float* W1 = (const float*)d_in[2];
    const float* b1 = (const float*)d_in[3];
    const float* W2 = (const float*)d_in[4];
    const float* b2 = (const float*)d_in[5];
    const float* Wo = (const float*)d_in[6];
    const float* bo = (const float*)d_in[7];
    float* out = (float*)d_out;

    const int N = in_sizes[0] / 128;   // 50000
    const int E = in_sizes[1] / 2;     // 400000
    const int* src = ei;
    const int* dst = ei + E;

    char* ws = (char*)d_ws;
    size_t off = 0;
    auto alloc = [&](size_t bytes) {
        void* p = ws + off;
        off += (bytes + 255) & ~(size_t)255;
        return p;
    };
    int* deg      = (int*)alloc((size_t)N * 4);
    int* rowstart = (int*)alloc((size_t)(N + 1) * 4);
    int* cursor   = (int*)alloc((size_t)N * 4);
    int* partial  = (int*)alloc((size_t)64 * 4);
    int* ebuf     = (int*)alloc((size_t)E * 4);
    float* logit  = (float*)alloc((size_t)N * 4);
    unsigned short* xb  = (unsigned short*)alloc((size_t)N * 128 * 2);
    unsigned short* W1b = (unsigned short*)alloc((size_t)512 * 256 * 2);
    unsigned short* W2b = (unsigned short*)alloc((size_t)512 * 1024 * 2);
    unsigned short* n1b = (unsigned short*)alloc((size_t)N * 128 * 2);
    unsigned short* h1b = (unsigned short*)alloc((size_t)N * 512 * 2);
    unsigned short* n2b = (unsigned short*)alloc((size_t)N * 512 * 2);
    (void)ws_size; (void)n_in; (void)out_size;

    hipMemsetAsync(deg,   0, (size_t)N * 4, stream);
    hipMemsetAsync(logit, 0, (size_t)N * 4, stream);

    // fused: cvt x/W1/W2 -> bf16  +  deg histogram (independent DAG roots)
    const int na4 = N * 128 / 4, nb4 = 512 * 256 / 4, nc4 = 512 * 1024 / 4;
    const int cvt_blocks  = ceil_div(na4 + nb4 + nc4, 256);
    const int hist_blocks = ceil_div(E, 256);
    cvt3_hist_kernel<<<cvt_blocks + hist_blocks, 256, 0, stream>>>(
        x, xb, na4, W1, W1b, nb4, W2, W2b, nc4, dst, deg, E, cvt_blocks);

    // CSR build (hierarchical scan)
    const int P = ceil_div(N, 1024);   // 49
    chunk_reduce<<<P, 256, 0, stream>>>(deg, partial, N);
    partial_scan<<<1, 64, 0, stream>>>(partial, rowstart + N, P);
    chunk_scan<<<P, 256, 0, stream>>>(deg, partial, rowstart, cursor, N);
    bucket_kernel<<<ceil_div(E, 256), 256, 0, stream>>>(src, dst, cursor, ebuf, E);

    // layer 1: 128^2-tile kernel (K=256, small) — XCD-swizzled 1D grid
    const int nrow = ceil_div(N, 128);              // 391
    const int gblocks = ceil_div(nrow, 8) * 8 * 4;  // 1568
    gather_mean_128<<<ceil_div(N * 64, 256), 256, 0, stream>>>(rowstart, ebuf,
                                                               (const unsigned*)xb, (unsigned*)n1b, N);
    gemm_mfma<<<gblocks, 256, 0, stream>>>(xb, n1b, W1b, b1, h1b, nullptr, nullptr,
                                           N, 128, 128, 512, 0);

    // layer 2 + fused head: 256^2-tile 8-phase kernel
    gather_mean_512<<<ceil_div(N * 64, 256), 256, 0, stream>>>(rowstart, ebuf, h1b, n2b, N);
    const int nrt2 = ceil_div(N, 256);              // 196 -> 392 blocks
    gemm2_8ph<<<nrt2 * 2, 512, 0, stream>>>(h1b, n2b, W2b, b2, Wo, logit, N);

    head_kernel<<<ceil_div(N, 256), 256, 0, stream>>>(logit, bo, out, N);
}

// Round 2
// 340.919 us; speedup vs baseline: 1.0280x; 1.0144x over previous
//
#include <hip/hip_runtime.h>
#include <math.h>

// ---------------------------------------------------------------------------
// GraphSAGE fraud detector. CSR-gather aggregation + bf16 MFMA GEMMs.
// R18: fix T2 swizzle in gemm2_8ph. R17's col^=(row_bit2<<5) was a 1-bit
// XOR that only permuted ds_read slots within {0..3} -> conflicts stayed
// at 4.8M. Correct form (guide G4): phys_col_byte = logical ^ ((row&7)<<4)
// -- 3-bit XOR over the 16B-slot index. Staging source col becomes
// c_log = 8*((l&7)^(l>>3)) elements; read swz = (cl&7)<<4. One ds_read_b128
// now lands 8 lanes x distinct-rows per slot = 8 acc/bank = exact minimum.
// Stage stream (unchanged from R17; vmcnt(4) gates, provably safe):
//   p0:Ah0(t1) p1:Ah1(t1) p2:Bh0(t2) p3:Bh1(t2)+GATE p4:Ah0(t2) p5:Ah1(t2)
//   p6:Bh0(t3) p7:Bh1(t3)+GATE   (t0=2j,t1=2j+1 computed; t2,t3 prefetched)
// MFMA 16x16x32 bf16: A-frag A[m=lane&15][k=quad*8+j]; C/D col=lane&15,
// row=quad*4+reg (m89/m97-verified layouts).
// ---------------------------------------------------------------------------

typedef __attribute__((ext_vector_type(8))) short bf16x8;   // 8 bf16, 4 VGPRs
typedef __attribute__((ext_vector_type(4))) float f32x4;

static inline int ceil_div(int a, int b) { return (a + b - 1) / b; }

__device__ inline float bf2f_lo(unsigned u) { return __builtin_bit_cast(float, u << 16); }
__device__ inline float bf2f_hi(unsigned u) { return __builtin_bit_cast(float, u & 0xffff0000u); }
__device__ inline unsigned f2bf(float f) {   // RNE round to bf16, bits in low 16
    unsigned u = __builtin_bit_cast(unsigned, f);
    u += 0x7fffu + ((u >> 16) & 1u);
    return u >> 16;
}

// async global->LDS, 16 B per lane; LDS dest = wave-uniform base + lane*16
#define GLOAD_LDS16(gp, lp)                                                   \
    __builtin_amdgcn_global_load_lds(                                         \
        (__attribute__((address_space(1))) void*)(gp),                        \
        (__attribute__((address_space(3))) void*)(lp), 16, 0, 0)

// ---------------- fused cvt(x,W1,W2) + deg histogram ----------------

__global__ void cvt3_hist_kernel(const float* __restrict__ a, unsigned short* __restrict__ ao, int na4,
                                 const float* __restrict__ b, unsigned short* __restrict__ bo, int nb4,
                                 const float* __restrict__ c, unsigned short* __restrict__ co, int nc4,
                                 const int* __restrict__ dst, int* __restrict__ deg, int E,
                                 int cvt_blocks) {
    if ((int)blockIdx.x < cvt_blocks) {
        int i = blockIdx.x * 256 + threadIdx.x;
        const float* in; unsigned short* out; int k;
        if (i < na4)                  { in = a; out = ao; k = i; }
        else if (i < na4 + nb4)       { in = b; out = bo; k = i - na4; }
        else if (i < na4 + nb4 + nc4) { in = c; out = co; k = i - na4 - nb4; }
        else return;
        float4 v = ((const float4*)in)[k];
        ushort4 o;
        o.x = (unsigned short)f2bf(v.x);
        o.y = (unsigned short)f2bf(v.y);
        o.z = (unsigned short)f2bf(v.z);
        o.w = (unsigned short)f2bf(v.w);
        ((ushort4*)out)[k] = o;
    } else {
        int e = (blockIdx.x - cvt_blocks) * 256 + threadIdx.x;
        if (e < E) atomicAdd(&deg[dst[e]], 1);
    }
}

// ---------------- CSR build ----------------

// per-1024-chunk sums
__global__ __launch_bounds__(256) void chunk_reduce(const int* __restrict__ deg,
                                                    int* __restrict__ partial, int N) {
    int base = blockIdx.x * 1024;
    int s = 0;
    for (int i = threadIdx.x; i < 1024; i += 256) {
        int idx = base + i;
        if (idx < N) s += deg[idx];
    }
    #pragma unroll
    for (int off = 32; off; off >>= 1) s += __shfl_down(s, off);
    __shared__ int ws[4];
    if ((threadIdx.x & 63) == 0) ws[threadIdx.x >> 6] = s;
    __syncthreads();
    if (threadIdx.x == 0) partial[blockIdx.x] = ws[0] + ws[1] + ws[2] + ws[3];
}

// exclusive scan of P<=64 partials (one wave); writes rowstart[N]=total
__global__ void partial_scan(int* __restrict__ partial, int* __restrict__ rowstartN, int P) {
    int lane = threadIdx.x;
    int v = (lane < P) ? partial[lane] : 0;
    int incl = v;
    #pragma unroll
    for (int off = 1; off < 64; off <<= 1) {
        int t = __shfl_up(incl, off);
        if (lane >= off) incl += t;
    }
    if (lane < P) partial[lane] = incl - v;
    if (lane == 63) *rowstartN = incl;
}

// per-chunk exclusive scan + global offset; writes rowstart and cursor
__global__ __launch_bounds__(256) void chunk_scan(const int* __restrict__ deg,
                                                  const int* __restrict__ partial,
                                                  int* __restrict__ rowstart,
                                                  int* __restrict__ cursor, int N) {
    int base = blockIdx.x * 1024 + threadIdx.x * 4;
    int v[4];
    #pragma unroll
    for (int j = 0; j < 4; ++j) {
        int i = base + j;
        v[j] = (i < N) ? deg[i] : 0;
    }
    int mysum = v[0] + v[1] + v[2] + v[3];
    int incl = mysum;
    int lane = threadIdx.x & 63, wave = threadIdx.x >> 6;
    #pragma unroll
    for (int off = 1; off < 64; off <<= 1) {
        int t = __shfl_up(incl, off);
        if (lane >= off) incl += t;
    }
    __shared__ int ws[4];
    if (lane == 63) ws[wave] = incl;
    __syncthreads();
    int run = partial[blockIdx.x] + incl - mysum;
    for (int w = 0; w < wave; ++w) run += ws[w];
    #pragma unroll
    for (int j = 0; j < 4; ++j) {
        int i = base + j;
        if (i < N) { rowstart[i] = run; cursor[i] = run; }
        run += v[j];
    }
}

__global__ void bucket_kernel(const int* __restrict__ src, const int* __restrict__ dst,
                              int* __restrict__ cursor, int* __restrict__ ebuf, int E) {
    int e = blockIdx.x * 256 + threadIdx.x;
    if (e < E) {
        int pos = atomicAdd(&cursor[dst[e]], 1);
        ebuf[pos] = src[e];
    }
}

// ---------------- gather means ----------------

// one wave per dst row; bf16 xb [N,128] -> bf16 mean [N,128]; fp32 accum
__global__ void gather_mean_128(const int* __restrict__ rowstart, const int* __restrict__ ebuf,
                                const unsigned* __restrict__ featb, unsigned* __restrict__ outb, int N) {
    int w = (blockIdx.x * blockDim.x + threadIdx.x) >> 6;
    int lane = threadIdx.x & 63;
    if (w >= N) return;
    int e0 = rowstart[w], e1 = rowstart[w + 1];
    float ax = 0.0f, ay = 0.0f;
    int i = e0;
    for (; i + 8 <= e1; i += 8) {           // 8-edge unroll for MLP
        unsigned v0 = featb[(size_t)ebuf[i]     * 64 + lane];
        unsigned v1 = featb[(size_t)ebuf[i + 1] * 64 + lane];
        unsigned v2 = featb[(size_t)ebuf[i + 2] * 64 + lane];
        unsigned v3 = featb[(size_t)ebuf[i + 3] * 64 + lane];
        unsigned v4 = featb[(size_t)ebuf[i + 4] * 64 + lane];
        unsigned v5 = featb[(size_t)ebuf[i + 5] * 64 + lane];
        unsigned v6 = featb[(size_t)ebuf[i + 6] * 64 + lane];
        unsigned v7 = featb[(size_t)ebuf[i + 7] * 64 + lane];
        ax += bf2f_lo(v0) + bf2f_lo(v1) + bf2f_lo(v2) + bf2f_lo(v3)
            + bf2f_lo(v4) + bf2f_lo(v5) + bf2f_lo(v6) + bf2f_lo(v7);
        ay += bf2f_hi(v0) + bf2f_hi(v1) + bf2f_hi(v2) + bf2f_hi(v3)
            + bf2f_hi(v4) + bf2f_hi(v5) + bf2f_hi(v6) + bf2f_hi(v7);
    }
    for (; i < e1; ++i) {
        unsigned v = featb[(size_t)ebuf[i] * 64 + lane];
        ax += bf2f_lo(v); ay += bf2f_hi(v);
    }
    float inv = 1.0f / fmaxf((float)(e1 - e0), 1.0f);
    outb[(size_t)w * 64 + lane] = f2bf(ax * inv) | (f2bf(ay * inv) << 16);
}

// one wave per dst row; bf16 feat [N,512] -> bf16 mean [N,512]; fp32 accum
__global__ void gather_mean_512(const int* __restrict__ rowstart, const int* __restrict__ ebuf,
                                const unsigned short* __restrict__ featb,
                                unsigned short* __restrict__ outb, int N) {
    int w = (blockIdx.x * blockDim.x + threadIdx.x) >> 6;
    int lane = threadIdx.x & 63;
    if (w >= N) return;
    int e0 = rowstart[w], e1 = rowstart[w + 1];
    float a[8] = {0, 0, 0, 0, 0, 0, 0, 0};
    const uint4* base = (const uint4*)featb;     // 512 bf16/row = 64 uint4/row
    int i = e0;
    for (; i + 8 <= e1; i += 8) {           // 8-edge unroll for MLP
        uint4 v0 = base[(size_t)ebuf[i]     * 64 + lane];
        uint4 v1 = base[(size_t)ebuf[i + 1] * 64 + lane];
        uint4 v2 = base[(size_t)ebuf[i + 2] * 64 + lane];
        uint4 v3 = base[(size_t)ebuf[i + 3] * 64 + lane];
        uint4 v4 = base[(size_t)ebuf[i + 4] * 64 + lane];
        uint4 v5 = base[(size_t)ebuf[i + 5] * 64 + lane];
        uint4 v6 = base[(size_t)ebuf[i + 6] * 64 + lane];
        uint4 v7 = base[(size_t)ebuf[i + 7] * 64 + lane];
        a[0] += bf2f_lo(v0.x) + bf2f_lo(v1.x) + bf2f_lo(v2.x) + bf2f_lo(v3.x)
              + bf2f_lo(v4.x) + bf2f_lo(v5.x) + bf2f_lo(v6.x) + bf2f_lo(v7.x);
        a[1] += bf2f_hi(v0.x) + bf2f_hi(v1.x) + bf2f_hi(v2.x) + bf2f_hi(v3.x)
              + bf2f_hi(v4.x) + bf2f_hi(v5.x) + bf2f_hi(v6.x) + bf2f_hi(v7.x);
        a[2] += bf2f_lo(v0.y) + bf2f_lo(v1.y) + bf2f_lo(v2.y) + bf2f_lo(v3.y)
              + bf2f_lo(v4.y) + bf2f_lo(v5.y) + bf2f_lo(v6.y) + bf2f_lo(v7.y);
        a[3] += bf2f_hi(v0.y) + bf2f_hi(v1.y) + bf2f_hi(v2.y) + bf2f_hi(v3.y)
              + bf2f_hi(v4.y) + bf2f_hi(v5.y) + bf2f_hi(v6.y) + bf2f_hi(v7.y);
        a[4] += bf2f_lo(v0.z) + bf2f_lo(v1.z) + bf2f_lo(v2.z) + bf2f_lo(v3.z)
              + bf2f_lo(v4.z) + bf2f_lo(v5.z) + bf2f_lo(v6.z) + bf2f_lo(v7.z);
        a[5] += bf2f_hi(v0.z) + bf2f_hi(v1.z) + bf2f_hi(v2.z) + bf2f_hi(v3.z)
              + bf2f_hi(v4.z) + bf2f_hi(v5.z) + bf2f_hi(v6.z) + bf2f_hi(v7.z);
        a[6] += bf2f_lo(v0.w) + bf2f_lo(v1.w) + bf2f_lo(v2.w) + bf2f_lo(v3.w)
              + bf2f_lo(v4.w) + bf2f_lo(v5.w) + bf2f_lo(v6.w) + bf2f_lo(v7.w);
        a[7] += bf2f_hi(v0.w) + bf2f_hi(v1.w) + bf2f_hi(v2.w) + bf2f_hi(v3.w)
              + bf2f_hi(v4.w) + bf2f_hi(v5.w) + bf2f_hi(v6.w) + bf2f_hi(v7.w);
    }
    for (; i < e1; ++i) {
        uint4 v = base[(size_t)ebuf[i] * 64 + lane];
        a[0] += bf2f_lo(v.x); a[1] += bf2f_hi(v.x);
        a[2] += bf2f_lo(v.y); a[3] += bf2f_hi(v.y);
        a[4] += bf2f_lo(v.z); a[5] += bf2f_hi(v.z);
        a[6] += bf2f_lo(v.w); a[7] += bf2f_hi(v.w);
    }
    float inv = 1.0f / fmaxf((float)(e1 - e0), 1.0f);
    uint4 o;
    o.x = f2bf(a[0] * inv) | (f2bf(a[1] * inv) << 16);
    o.y = f2bf(a[2] * inv) | (f2bf(a[3] * inv) << 16);
    o.z = f2bf(a[4] * inv) | (f2bf(a[5] * inv) << 16);
    o.w = f2bf(a[6] * inv) | (f2bf(a[7] * inv) << 16);
    ((uint4*)outb)[(size_t)w * 64 + lane] = o;
}

// ---------------- bf16 MFMA GEMM (R12-exact: BK=32, XCD swizzle) -----------
// Retained for layer 1 (K=256). T2 is measured-NULL on 2-phase structures.
__global__ __launch_bounds__(256) void gemm_mfma(
    const unsigned short* __restrict__ A0,   // [N, K0] bf16
    const unsigned short* __restrict__ A1,   // [N, K1] bf16, K1 == K0
    const unsigned short* __restrict__ W,    // [C, K0+K1] bf16 row-major
    const float* __restrict__ b,             // [C] fp32
    unsigned short* __restrict__ outb,       // [N, C] bf16 (mode 0)
    const float* __restrict__ Wo,            // [C] fp32    (mode 1)
    float* __restrict__ logit,               // [N] fp32    (mode 1)
    int N, int K0, int K1, int C, int mode)
{
    // --- XCD-aware decode ---
    const int nrow = (N + 127) >> 7;
    const int id   = blockIdx.x;
    const int rowb = ((id >> 5) << 3) + (id & 7);   // rslot*8 + xcd
    const int colb = (id >> 3) & 3;
    if (rowb >= nrow) return;

    const int K = K0 + K1;
    const int S = K0;               // row stride of both A0 and A1
    __shared__ short As[2][4096];   // [128][32] per buffer, 8 KB
    __shared__ short Bs[2][4096];

    const int tid  = threadIdx.x;
    const int lane = tid & 63;
    const int wave = tid >> 6;
    const int wm = wave & 1, wn = wave >> 1;
    const int cl = lane & 15, quad = lane >> 4;
    const int row0 = rowb * 128;
    const int col0 = colb * 128;

    // staging: lane = 4r+j; wave w, load i covers tile rows w*32+i*16 .. +16
    const int r = lane >> 2;        // 0..15
    const int j = lane & 3;         // 16B chunk within the row's 64B K-slice
    const int trow0 = wave * 32 + r;
    const int trow1 = trow0 + 16;
    // clamp OOB tile rows to N-1 (loaded garbage discarded by epilogue guard)
    const int ar0 = (row0 + trow0 < N) ? row0 + trow0 : N - 1;
    const int ar1 = (row0 + trow1 < N) ? row0 + trow1 : N - 1;
    const size_t aoff0 = (size_t)ar0 * S + j * 8;
    const size_t aoff1 = (size_t)ar1 * S + j * 8;
    const size_t boff0 = (size_t)(col0 + trow0) * K + j * 8;
    const size_t boff1 = (size_t)(col0 + trow1) * K + j * 8;
    const int lds0 = (wave * 32) * 32;        // shorts; wave-uniform
    const int lds1 = (wave * 32 + 16) * 32;

    f32x4 acc[4][4];
    #pragma unroll
    for (int mt = 0; mt < 4; ++mt)
        #pragma unroll
        for (int nt = 0; nt < 4; ++nt)
            acc[mt][nt] = (f32x4){0.f, 0.f, 0.f, 0.f};

    // prologue: DMA tile 0 into buffer 0
    GLOAD_LDS16(A0 + aoff0, &As[0][lds0]);
    GLOAD_LDS16(A0 + aoff1, &As[0][lds1]);
    GLOAD_LDS16(W  + boff0, &Bs[0][lds0]);
    GLOAD_LDS16(W  + boff1, &Bs[0][lds1]);

    const int iters = K >> 5;
    for (int i = 0; i < iters; ++i) {
        const int cur = i & 1;
        // barrier drains tile i's DMA (vmcnt0) and fences tile i-1 frag reads
        __syncthreads();
        if (i + 1 < iters) {
            const int kn = (i + 1) << 5;
            const unsigned short* Ab = (kn < K0) ? (A0 + kn) : (A1 + (kn - K0));
            const unsigned short* Wb = W + kn;
            const int nb = cur ^ 1;
            GLOAD_LDS16(Ab + aoff0, &As[nb][lds0]);
            GLOAD_LDS16(Ab + aoff1, &As[nb][lds1]);
            GLOAD_LDS16(Wb + boff0, &Bs[nb][lds0]);
            GLOAD_LDS16(Wb + boff1, &Bs[nb][lds1]);
        }

        bf16x8 af[4], bfr[4];
        #pragma unroll
        for (int mt = 0; mt < 4; ++mt)
            af[mt] = *(const bf16x8*)&As[cur][(wm * 64 + mt * 16 + cl) * 32 + quad * 8];
        #pragma unroll
        for (int nt = 0; nt < 4; ++nt)
            bfr[nt] = *(const bf16x8*)&Bs[cur][(wn * 64 + nt * 16 + cl) * 32 + quad * 8];

        #pragma unroll
        for (int mt = 0; mt < 4; ++mt)
            #pragma unroll
            for (int nt = 0; nt < 4; ++nt)
                acc[mt][nt] = __builtin_amdgcn_mfma_f32_16x16x32_bf16(
                    af[mt], bfr[nt], acc[mt][nt], 0, 0, 0);
    }

    if (mode == 0) {
        #pragma unroll
        for (int nt = 0; nt < 4; ++nt) {
            const int colx = col0 + wn * 64 + nt * 16 + cl;
            const float bb = b[colx];
            #pragma unroll
            for (int mt = 0; mt < 4; ++mt) {
                #pragma unroll
                for (int rr = 0; rr < 4; ++rr) {
                    int row = row0 + wm * 64 + mt * 16 + quad * 4 + rr;
                    if (row < N)
                        outb[(size_t)row * C + colx] =
                            (unsigned short)f2bf(fmaxf(acc[mt][nt][rr] + bb, 0.0f));
                }
            }
        }
    } else {
        float bv[4], wv2[4];
        #pragma unroll
        for (int nt = 0; nt < 4; ++nt) {
            const int colx = col0 + wn * 64 + nt * 16 + cl;
            bv[nt] = b[colx];
            wv2[nt] = Wo[colx];
        }
        #pragma unroll
        for (int mt = 0; mt < 4; ++mt) {
            #pragma unroll
            for (int rr = 0; rr < 4; ++rr) {
                float s = 0.0f;
                #pragma unroll
                for (int nt = 0; nt < 4; ++nt)
                    s += fmaxf(acc[mt][nt][rr] + bv[nt], 0.0f) * wv2[nt];
                s += __shfl_xor(s, 1);
                s += __shfl_xor(s, 2);
                s += __shfl_xor(s, 4);
                s += __shfl_xor(s, 8);
                int row = row0 + wm * 64 + mt * 16 + quad * 4 + rr;
                if (cl == 0 && row < N) atomicAdd(&logit[row], s);
            }
        }
    }
}

// ---------------- layer-2: 256x256-tile 8-phase GEMM + fused head ----------
// C = relu([A0|A1] @ W^T + b); logit[row] += sum_col C[row,col]*Wo[col].
// Fixed shape: A row stride 512 (K0=K1=512, K=1024), W [512][1024].
// 512 thr = 8 waves (2Mx4N); wave tile 128x64; BK=64; 2 K-tiles per iter,
// 8 phases per iter, 16 MFMA per phase. LDS 128 KiB (2 dbuf x (A 32K + B 32K)).
// T2 swizzle (3-bit, G4 form): phys_col_byte = logical ^ ((row&7)<<4).
// Linear LDS dest (global_load_lds), inverse-swizzled GLOBAL source
// (c_log = 8*((l&7)^(l>>3)) elements), swizzled ds_read (swz=(cl&7)<<4).
// Counted vmcnt(4) gates at p3/p7; one lgkmcnt(0) per phase; setprio on MFMA.

#define KT2  16   // K-tiles of 64 (K = 1024)
#define NIT2 8    // iterations (2 K-tiles each)

#define STG_A(hh, kt, buf) do {                                                        \
    const unsigned short* _pA = ((kt) < 8) ? A0 : A1;                                  \
    const size_t _ko = (size_t)(((kt) & 7) << 6);                                      \
    GLOAD_LDS16(_pA + _ko + offA[hh][0],                                               \
                lds + (buf) * 65536 + (hh) * 16384 + (w * 2 + 0) * 1024);              \
    GLOAD_LDS16(_pA + _ko + offA[hh][1],                                               \
                lds + (buf) * 65536 + (hh) * 16384 + (w * 2 + 1) * 1024);              \
} while (0)

#define STG_B(hh, kt, buf) do {                                                        \
    const size_t _ko = (size_t)((kt) << 6);                                            \
    GLOAD_LDS16(W + _ko + offB[hh][0],                                                 \
                lds + (buf) * 65536 + 32768 + (hh) * 16384 + (w * 2 + 0) * 1024);      \
    GLOAD_LDS16(W + _ko + offB[hh][1],                                                 \
                lds + (buf) * 65536 + 32768 + (hh) * 16384 + (w * 2 + 1) * 1024);      \
} while (0)

#define RD_A8(qm, buf) do {                                                            \
    _Pragma("unroll")                                                                  \
    for (int _m = 0; _m < 4; ++_m) {                                                   \
        af[_m][0] = *(const bf16x8*)(lds + (buf) * 65536 +                             \
                    ((aBase + ((qm) * 4 + _m) * 2048) ^ swz));                         \
        af[_m][1] = *(const bf16x8*)(lds + (buf) * 65536 +                             \
                    ((aBase + ((qm) * 4 + _m) * 2048 + 64) ^ swz));                    \
    }                                                                                  \
} while (0)

#define RD_B4(qn, buf) do {                                                            \
    _Pragma("unroll")                                                                  \
    for (int _n = 0; _n < 2; ++_n) {                                                   \
        bq[(qn) * 2 + _n][0] = *(const bf16x8*)(lds + (buf) * 65536 +                  \
                    ((bBase + ((qn) * 2 + _n) * 2048) ^ swz));                         \
        bq[(qn) * 2 + _n][1] = *(const bf16x8*)(lds + (buf) * 65536 +                  \
                    ((bBase + ((qn) * 2 + _n) * 2048 + 64) ^ swz));                    \
    }                                                                                  \
} while (0)

#define MFMA16(qm, qn) do {                                                            \
    _Pragma("unroll")                                                                  \
    for (int _kk = 0; _kk < 2; ++_kk)                                                  \
        _Pragma("unroll")                                                              \
        for (int _m = 0; _m < 4; ++_m)                                                 \
            _Pragma("unroll")                                                          \
            for (int _n = 0; _n < 2; ++_n)                                             \
                acc[(qm) * 4 + _m][(qn) * 2 + _n] =                                    \
                    __builtin_amdgcn_mfma_f32_16x16x32_bf16(                           \
                        af[_m][_kk], bq[(qn) * 2 + _n][_kk],                           \
                        acc[(qm) * 4 + _m][(qn) * 2 + _n], 0, 0, 0);                   \
} while (0)

#define PH_SYNC_MFMA(qm, qn) do {                                                      \
    __builtin_amdgcn_sched_barrier(0);                                                 \
    __builtin_amdgcn_s_barrier();                                                      \
    __builtin_amdgcn_sched_barrier(0);                                                 \
    asm volatile("s_waitcnt lgkmcnt(0)" ::: "memory");                                 \
    __builtin_amdgcn_s_setprio(1);                                                     \
    MFMA16(qm, qn);                                                                    \
    __builtin_amdgcn_s_setprio(0);                                                     \
    __builtin_amdgcn_sched_barrier(0);                                                 \
    __builtin_amdgcn_s_barrier();                                                      \
    __builtin_amdgcn_sched_barrier(0);                                                 \
} while (0)

__global__ __launch_bounds__(512, 2) void gemm2_8ph(
    const unsigned short* __restrict__ A0,   // h1b [N,512] bf16
    const unsigned short* __restrict__ A1,   // n2b [N,512] bf16
    const unsigned short* __restrict__ W,    // W2b [512,1024] bf16
    const float* __restrict__ b,             // b2 [512]
    const float* __restrict__ Wo,            // [512]
    float* __restrict__ logit,               // [N]
    int N)
{
    __shared__ char lds[131072];             // 2 dbuf x (A 32K | B 32K)

    // XCD-aware swizzle: col siblings of a row-tile on one XCD (A L2-reuse)
    const int nrt = (N + 255) >> 8;
    const int nb  = nrt * 2;
    const int orig = blockIdx.x;
    int virt = orig;
    if ((nb & 7) == 0) virt = (orig & 7) * (nb >> 3) + (orig >> 3);
    const int row0 = (virt >> 1) << 8;
    const int col0 = (virt & 1) << 8;

    const int tid = threadIdx.x;
    const int w = tid >> 6, l = tid & 63;
    const int wr = w >> 2, wc = w & 3;       // 2x4 wave grid
    const int cl = l & 15, quad = l >> 4;

    // ---- staging addresses (inverse-swizzled global source; linear dest) ----
    // dest byte t = hh*16384 + (w*2+i)*1024 + l*16  ->  row = (w*2+i)*8+(l>>3),
    // phys col = (l&7)*16 B. Need col_log = col_phys ^ ((row&7)<<4), row&7=l>>3:
    // c_log = 16*((l&7) ^ (l>>3)) bytes = 8*((l&7)^(l>>3)) elements.
    const int c_log = ((l & 7) ^ (l >> 3)) * 8;
    size_t offA[2][2], offB[2][2];
    #pragma unroll
    for (int hh = 0; hh < 2; ++hh)
        #pragma unroll
        for (int i = 0; i < 2; ++i) {
            int ra = row0 + hh * 128 + (w * 2 + i) * 8 + (l >> 3);
            if (ra > N - 1) ra = N - 1;      // clamp; epilogue guards row<N
            offA[hh][i] = (size_t)ra * 512 + c_log;
            const int rb = col0 + hh * 128 + (w * 2 + i) * 8 + (l >> 3);
            offB[hh][i] = (size_t)rb * 1024 + c_log;
        }

    // ---- ds_read: phys = logical ^ ((row&7)<<4); row&7 = cl&7 for both A,B
    const int swz   = (cl & 7) << 4;
    const int aBase = wr * 16384 + cl * 128 + quad * 16;           // + mt*2048 + kk*64
    const int bBase = 32768 + (wc * 64 + cl) * 128 + quad * 16;    // + nt*2048 + kk*64

    f32x4 acc[8][4];
    #pragma unroll
    for (int mt = 0; mt < 8; ++mt)
        #pragma unroll
        for (int nt = 0; nt < 4; ++nt)
            acc[mt][nt] = (f32x4){0.f, 0.f, 0.f, 0.f};

    bf16x8 af[4][2];     // A frags of current qm group
    bf16x8 bq[4][2];     // all B frags of current K-tile

    // ---- prologue: t0 fully (8 instr), then B(t1) (4 instr) ----
    STG_A(0, 0, 0); STG_A(1, 0, 0);
    STG_B(0, 0, 0); STG_B(1, 0, 0);
    STG_B(0, 1, 1); STG_B(1, 1, 1);
    asm volatile("s_waitcnt vmcnt(4)" ::: "memory");   // t0 landed; B(t1) may fly
    __builtin_amdgcn_s_barrier();
    __builtin_amdgcn_sched_barrier(0);

    for (int j = 0; j < NIT2; ++j) {
        const int t1 = 2 * j + 1;
        const int t2 = (2 * j + 2 < KT2) ? 2 * j + 2 : KT2 - 2;  // clamped, even
        const int t3 = (2 * j + 3 < KT2) ? 2 * j + 3 : KT2 - 1;  // clamped, odd
        // ---- K-tile t0 = 2j (buf0) ----
        RD_A8(0, 0); RD_B4(0, 0);                 // 12 ds_reads
        STG_A(0, t1, 1);                          // overwrites A(t1-2), last read prev p6
        asm volatile("s_waitcnt lgkmcnt(8)" ::: "memory");
        PH_SYNC_MFMA(0, 0);                       // p0
        RD_B4(1, 0);
        STG_A(1, t1, 1);
        PH_SYNC_MFMA(0, 1);                       // p1
        RD_A8(1, 0);
        STG_B(0, t2, 0);                          // overwrites B(t0), last read p1
        PH_SYNC_MFMA(1, 1);                       // p2
        STG_B(1, t2, 0);
        asm volatile("s_waitcnt vmcnt(4)" ::: "memory");   // GATE t1: A@p0,p1 landed
        PH_SYNC_MFMA(1, 0);                       // p3
        // ---- K-tile t1 = 2j+1 (buf1) ----
        RD_A8(0, 1); RD_B4(0, 1);
        STG_A(0, t2, 0);                          // overwrites A(t0), last read p2
        asm volatile("s_waitcnt lgkmcnt(8)" ::: "memory");
        PH_SYNC_MFMA(0, 0);                       // p4
        RD_B4(1, 1);
        STG_A(1, t2, 0);
        PH_SYNC_MFMA(0, 1);                       // p5
        RD_A8(1, 1);
        STG_B(0, t3, 1);                          // overwrites B(t1), last read p5
        PH_SYNC_MFMA(1, 1);                       // p6
        STG_B(1, t3, 1);
        asm volatile("s_waitcnt vmcnt(4)" ::: "memory");   // GATE t2: B@p2,p3 A@p4,p5
        PH_SYNC_MFMA(1, 0);                       // p7
    }
    asm volatile("s_waitcnt vmcnt(0)" ::: "memory");   // drain tail stages

    // ---- epilogue: fused ReLU + Wo dot + atomic row add ----
    float bv[4], wv[4];
    #pragma unroll
    for (int nt = 0; nt < 4; ++nt) {
        const int colx = col0 + wc * 64 + nt * 16 + cl;
        bv[nt] = b[colx];
        wv[nt] = Wo[colx];
    }
    #pragma unroll
    for (int mt = 0; mt < 8; ++mt) {
        #pragma unroll
        for (int rr = 0; rr < 4; ++rr) {
            float s = 0.0f;
            #pragma unroll
            for (int nt = 0; nt < 4; ++nt)
                s += fmaxf(acc[mt][nt][rr] + bv[nt], 0.0f) * wv[nt];
            s += __shfl_xor(s, 1);
            s += __shfl_xor(s, 2);
            s += __shfl_xor(s, 4);
            s += __shfl_xor(s, 8);
            const int row = row0 + wr * 128 + mt * 16 + quad * 4 + rr;
            if (cl == 0 && row < N) atomicAdd(&logit[row], s);
        }
    }
}

__global__ void head_kernel(const float* __restrict__ logit, const float* __restrict__ bo,
                            float* __restrict__ out, int N) {
    int i = blockIdx.x * 256 + threadIdx.x;
    if (i < N) out[i] = 1.0f / (1.0f + expf(-(logit[i] + bo[0])));
}

extern "C" void kernel_launch(void* const* d_in, const int* in_sizes, int n_in,
                              void* d_out, int out_size, void* d_ws, size_t ws_size,
                              hipStream_t stream) {
    const float* x  = (const float*)d_in[0];
    const int*   ei = (const int*)d_in[1];
    const float* W1 = (const float*)d_in[2];
    const float* b1 = (const float*)d_in[3];
    const float* W2 = (const float*)d_in[4];
    const float* b2 = (const float*)d_in[5];
    const float* Wo = (const float*)d_in[6];
    const float* bo = (const float*)d_in[7];
    float* out = (float*)d_out;

    const int N = in_sizes[0] / 128;   // 50000
    const int E = in_sizes[1] / 2;     // 400000
    const int* src = ei;
    const int* dst = ei + E;

    char* ws = (char*)d_ws;
    size_t off = 0;
    auto alloc = [&](size_t bytes) {
        void* p = ws + off;
        off += (bytes + 255) & ~(size_t)255;
        return p;
    };
    int* deg      = (int*)alloc((size_t)N * 4);
    int* rowstart = (int*)alloc((size_t)(N + 1) * 4);
    int* cursor   = (int*)alloc((size_t)N * 4);
    int* partial  = (int*)alloc((size_t)64 * 4);
    int* ebuf     = (int*)alloc((size_t)E * 4);
    float* logit  = (float*)alloc((size_t)N * 4);
    unsigned short* xb  = (unsigned short*)alloc((size_t)N * 128 * 2);
    unsigned short* W1b = (unsigned short*)alloc((size_t)512 * 256 * 2);
    unsigned short* W2b = (unsigned short*)alloc((size_t)512 * 1024 * 2);
    unsigned short* n1b = (unsigned short*)alloc((size_t)N * 128 * 2);
    unsigned short* h1b = (unsigned short*)alloc((size_t)N * 512 * 2);
    unsigned short* n2b = (unsigned short*)alloc((size_t)N * 512 * 2);
    (void)ws_size; (void)n_in; (void)out_size;

    hipMemsetAsync(deg,   0, (size_t)N * 4, stream);
    hipMemsetAsync(logit, 0, (size_t)N * 4, stream);

    // fused: cvt x/W1/W2 -> bf16  +  deg histogram (independent DAG roots)
    const int na4 = N * 128 / 4, nb4 = 512 * 256 / 4, nc4 = 512 * 1024 / 4;
    const int cvt_blocks  = ceil_div(na4 + nb4 + nc4, 256);
    const int hist_blocks = ceil_div(E, 256);
    cvt3_hist_kernel<<<cvt_blocks + hist_blocks, 256, 0, stream>>>(
        x, xb, na4, W1, W1b, nb4, W2, W2b, nc4, dst, deg, E, cvt_blocks);

    // CSR build (hierarchical scan)
    const int P = ceil_div(N, 1024);   // 49
    chunk_reduce<<<P, 256, 0, stream>>>(deg, partial, N);
    partial_scan<<<1, 64, 0, stream>>>(partial, rowstart + N, P);
    chunk_scan<<<P, 256, 0, stream>>>(deg, partial, rowstart, cursor, N);
    bucket_kernel<<<ceil_div(E, 256), 256, 0, stream>>>(src, dst, cursor, ebuf, E);

    // layer 1: 128^2-tile kernel (K=256, small) — XCD-swizzled 1D grid
    const int nrow = ceil_div(N, 128);              // 391
    const int gblocks = ceil_div(nrow, 8) * 8 * 4;  // 1568
    gather_mean_128<<<ceil_div(N * 64, 256), 256, 0, stream>>>(rowstart, ebuf,
                                                               (const unsigned*)xb, (unsigned*)n1b, N);
    gemm_mfma<<<gblocks, 256, 0, stream>>>(xb, n1b, W1b, b1, h1b, nullptr, nullptr,
                                           N, 128, 128, 512, 0);

    // layer 2 + fused head: 256^2-tile 8-phase kernel
    gather_mean_512<<<ceil_div(N * 64, 256), 256, 0, stream>>>(rowstart, ebuf, h1b, n2b, N);
    const int nrt2 = ceil_div(N, 256);              // 196 -> 392 blocks
    gemm2_8ph<<<nrt2 * 2, 512, 0, stream>>>(h1b, n2b, W2b, b2, Wo, logit, N);

    head_kernel<<<ceil_div(N, 256), 256, 0, stream>>>(logit, bo, out, N);
}

// Round 3
// 337.609 us; speedup vs baseline: 1.0381x; 1.0098x over previous
//
#include <hip/hip_runtime.h>
#include <math.h>

// ---------------------------------------------------------------------------
// GraphSAGE fraud detector. CSR-gather aggregation + bf16 MFMA GEMMs.
// R19: single-barrier phases in gemm2_8ph. R18 zeroed LDS bank conflicts
// (4.8M -> 0) but only -7us: the double-barrier-per-phase lockstep
// serializes LDS traffic (~2000cy/K-tile) against MFMA (~2048cy/K-tile).
// The MFMA-cluster barrier is not needed for correctness (MFMA reads regs;
// slot overwrites are >=2 phase-opens after last ds_read; vmcnt gates sit
// before a phase-open join). One barrier per phase halves barrier count and
// lets one wave's ds_reads overlap a sibling's MFMA. Manual lgkmcnt dropped
// (compiler tracks ds_read deps); vmcnt gates kept (DMA dep is invisible).
// Stage stream (unchanged; vmcnt(4) gates at p3/p7):
//   p0:Ah0(t1) p1:Ah1(t1) p2:Bh0(t2) p3:Bh1(t2)+GATE p4:Ah0(t2) p5:Ah1(t2)
//   p6:Bh0(t3) p7:Bh1(t3)+GATE   (t0=2j,t1=2j+1 computed; t2,t3 prefetched)
// T2 swizzle (R18, verified): phys_col_byte = logical ^ ((row&7)<<4);
// linear LDS dest, inverse-swizzled global src c_log=8*((l&7)^(l>>3)),
// read swz=(cl&7)<<4.
// MFMA 16x16x32 bf16: A-frag A[m=lane&15][k=quad*8+j]; C/D col=lane&15,
// row=quad*4+reg (m89/m97-verified layouts).
// ---------------------------------------------------------------------------

typedef __attribute__((ext_vector_type(8))) short bf16x8;   // 8 bf16, 4 VGPRs
typedef __attribute__((ext_vector_type(4))) float f32x4;

static inline int ceil_div(int a, int b) { return (a + b - 1) / b; }

__device__ inline float bf2f_lo(unsigned u) { return __builtin_bit_cast(float, u << 16); }
__device__ inline float bf2f_hi(unsigned u) { return __builtin_bit_cast(float, u & 0xffff0000u); }
__device__ inline unsigned f2bf(float f) {   // RNE round to bf16, bits in low 16
    unsigned u = __builtin_bit_cast(unsigned, f);
    u += 0x7fffu + ((u >> 16) & 1u);
    return u >> 16;
}

// async global->LDS, 16 B per lane; LDS dest = wave-uniform base + lane*16
#define GLOAD_LDS16(gp, lp)                                                   \
    __builtin_amdgcn_global_load_lds(                                         \
        (__attribute__((address_space(1))) void*)(gp),                        \
        (__attribute__((address_space(3))) void*)(lp), 16, 0, 0)

// ---------------- fused cvt(x,W1,W2) + deg histogram ----------------

__global__ void cvt3_hist_kernel(const float* __restrict__ a, unsigned short* __restrict__ ao, int na4,
                                 const float* __restrict__ b, unsigned short* __restrict__ bo, int nb4,
                                 const float* __restrict__ c, unsigned short* __restrict__ co, int nc4,
                                 const int* __restrict__ dst, int* __restrict__ deg, int E,
                                 int cvt_blocks) {
    if ((int)blockIdx.x < cvt_blocks) {
        int i = blockIdx.x * 256 + threadIdx.x;
        const float* in; unsigned short* out; int k;
        if (i < na4)                  { in = a; out = ao; k = i; }
        else if (i < na4 + nb4)       { in = b; out = bo; k = i - na4; }
        else if (i < na4 + nb4 + nc4) { in = c; out = co; k = i - na4 - nb4; }
        else return;
        float4 v = ((const float4*)in)[k];
        ushort4 o;
        o.x = (unsigned short)f2bf(v.x);
        o.y = (unsigned short)f2bf(v.y);
        o.z = (unsigned short)f2bf(v.z);
        o.w = (unsigned short)f2bf(v.w);
        ((ushort4*)out)[k] = o;
    } else {
        int e = (blockIdx.x - cvt_blocks) * 256 + threadIdx.x;
        if (e < E) atomicAdd(&deg[dst[e]], 1);
    }
}

// ---------------- CSR build ----------------

// per-1024-chunk sums
__global__ __launch_bounds__(256) void chunk_reduce(const int* __restrict__ deg,
                                                    int* __restrict__ partial, int N) {
    int base = blockIdx.x * 1024;
    int s = 0;
    for (int i = threadIdx.x; i < 1024; i += 256) {
        int idx = base + i;
        if (idx < N) s += deg[idx];
    }
    #pragma unroll
    for (int off = 32; off; off >>= 1) s += __shfl_down(s, off);
    __shared__ int ws[4];
    if ((threadIdx.x & 63) == 0) ws[threadIdx.x >> 6] = s;
    __syncthreads();
    if (threadIdx.x == 0) partial[blockIdx.x] = ws[0] + ws[1] + ws[2] + ws[3];
}

// exclusive scan of P<=64 partials (one wave); writes rowstart[N]=total
__global__ void partial_scan(int* __restrict__ partial, int* __restrict__ rowstartN, int P) {
    int lane = threadIdx.x;
    int v = (lane < P) ? partial[lane] : 0;
    int incl = v;
    #pragma unroll
    for (int off = 1; off < 64; off <<= 1) {
        int t = __shfl_up(incl, off);
        if (lane >= off) incl += t;
    }
    if (lane < P) partial[lane] = incl - v;
    if (lane == 63) *rowstartN = incl;
}

// per-chunk exclusive scan + global offset; writes rowstart and cursor
__global__ __launch_bounds__(256) void chunk_scan(const int* __restrict__ deg,
                                                  const int* __restrict__ partial,
                                                  int* __restrict__ rowstart,
                                                  int* __restrict__ cursor, int N) {
    int base = blockIdx.x * 1024 + threadIdx.x * 4;
    int v[4];
    #pragma unroll
    for (int j = 0; j < 4; ++j) {
        int i = base + j;
        v[j] = (i < N) ? deg[i] : 0;
    }
    int mysum = v[0] + v[1] + v[2] + v[3];
    int incl = mysum;
    int lane = threadIdx.x & 63, wave = threadIdx.x >> 6;
    #pragma unroll
    for (int off = 1; off < 64; off <<= 1) {
        int t = __shfl_up(incl, off);
        if (lane >= off) incl += t;
    }
    __shared__ int ws[4];
    if (lane == 63) ws[wave] = incl;
    __syncthreads();
    int run = partial[blockIdx.x] + incl - mysum;
    for (int w = 0; w < wave; ++w) run += ws[w];
    #pragma unroll
    for (int j = 0; j < 4; ++j) {
        int i = base + j;
        if (i < N) { rowstart[i] = run; cursor[i] = run; }
        run += v[j];
    }
}

__global__ void bucket_kernel(const int* __restrict__ src, const int* __restrict__ dst,
                              int* __restrict__ cursor, int* __restrict__ ebuf, int E) {
    int e = blockIdx.x * 256 + threadIdx.x;
    if (e < E) {
        int pos = atomicAdd(&cursor[dst[e]], 1);
        ebuf[pos] = src[e];
    }
}

// ---------------- gather means ----------------

// one wave per dst row; bf16 xb [N,128] -> bf16 mean [N,128]; fp32 accum
__global__ void gather_mean_128(const int* __restrict__ rowstart, const int* __restrict__ ebuf,
                                const unsigned* __restrict__ featb, unsigned* __restrict__ outb, int N) {
    int w = (blockIdx.x * blockDim.x + threadIdx.x) >> 6;
    int lane = threadIdx.x & 63;
    if (w >= N) return;
    int e0 = rowstart[w], e1 = rowstart[w + 1];
    float ax = 0.0f, ay = 0.0f;
    int i = e0;
    for (; i + 8 <= e1; i += 8) {           // 8-edge unroll for MLP
        unsigned v0 = featb[(size_t)ebuf[i]     * 64 + lane];
        unsigned v1 = featb[(size_t)ebuf[i + 1] * 64 + lane];
        unsigned v2 = featb[(size_t)ebuf[i + 2] * 64 + lane];
        unsigned v3 = featb[(size_t)ebuf[i + 3] * 64 + lane];
        unsigned v4 = featb[(size_t)ebuf[i + 4] * 64 + lane];
        unsigned v5 = featb[(size_t)ebuf[i + 5] * 64 + lane];
        unsigned v6 = featb[(size_t)ebuf[i + 6] * 64 + lane];
        unsigned v7 = featb[(size_t)ebuf[i + 7] * 64 + lane];
        ax += bf2f_lo(v0) + bf2f_lo(v1) + bf2f_lo(v2) + bf2f_lo(v3)
            + bf2f_lo(v4) + bf2f_lo(v5) + bf2f_lo(v6) + bf2f_lo(v7);
        ay += bf2f_hi(v0) + bf2f_hi(v1) + bf2f_hi(v2) + bf2f_hi(v3)
            + bf2f_hi(v4) + bf2f_hi(v5) + bf2f_hi(v6) + bf2f_hi(v7);
    }
    for (; i < e1; ++i) {
        unsigned v = featb[(size_t)ebuf[i] * 64 + lane];
        ax += bf2f_lo(v); ay += bf2f_hi(v);
    }
    float inv = 1.0f / fmaxf((float)(e1 - e0), 1.0f);
    outb[(size_t)w * 64 + lane] = f2bf(ax * inv) | (f2bf(ay * inv) << 16);
}

// one wave per dst row; bf16 feat [N,512] -> bf16 mean [N,512]; fp32 accum
__global__ void gather_mean_512(const int* __restrict__ rowstart, const int* __restrict__ ebuf,
                                const unsigned short* __restrict__ featb,
                                unsigned short* __restrict__ outb, int N) {
    int w = (blockIdx.x * blockDim.x + threadIdx.x) >> 6;
    int lane = threadIdx.x & 63;
    if (w >= N) return;
    int e0 = rowstart[w], e1 = rowstart[w + 1];
    float a[8] = {0, 0, 0, 0, 0, 0, 0, 0};
    const uint4* base = (const uint4*)featb;     // 512 bf16/row = 64 uint4/row
    int i = e0;
    for (; i + 8 <= e1; i += 8) {           // 8-edge unroll for MLP
        uint4 v0 = base[(size_t)ebuf[i]     * 64 + lane];
        uint4 v1 = base[(size_t)ebuf[i + 1] * 64 + lane];
        uint4 v2 = base[(size_t)ebuf[i + 2] * 64 + lane];
        uint4 v3 = base[(size_t)ebuf[i + 3] * 64 + lane];
        uint4 v4 = base[(size_t)ebuf[i + 4] * 64 + lane];
        uint4 v5 = base[(size_t)ebuf[i + 5] * 64 + lane];
        uint4 v6 = base[(size_t)ebuf[i + 6] * 64 + lane];
        uint4 v7 = base[(size_t)ebuf[i + 7] * 64 + lane];
        a[0] += bf2f_lo(v0.x) + bf2f_lo(v1.x) + bf2f_lo(v2.x) + bf2f_lo(v3.x)
              + bf2f_lo(v4.x) + bf2f_lo(v5.x) + bf2f_lo(v6.x) + bf2f_lo(v7.x);
        a[1] += bf2f_hi(v0.x) + bf2f_hi(v1.x) + bf2f_hi(v2.x) + bf2f_hi(v3.x)
              + bf2f_hi(v4.x) + bf2f_hi(v5.x) + bf2f_hi(v6.x) + bf2f_hi(v7.x);
        a[2] += bf2f_lo(v0.y) + bf2f_lo(v1.y) + bf2f_lo(v2.y) + bf2f_lo(v3.y)
              + bf2f_lo(v4.y) + bf2f_lo(v5.y) + bf2f_lo(v6.y) + bf2f_lo(v7.y);
        a[3] += bf2f_hi(v0.y) + bf2f_hi(v1.y) + bf2f_hi(v2.y) + bf2f_hi(v3.y)
              + bf2f_hi(v4.y) + bf2f_hi(v5.y) + bf2f_hi(v6.y) + bf2f_hi(v7.y);
        a[4] += bf2f_lo(v0.z) + bf2f_lo(v1.z) + bf2f_lo(v2.z) + bf2f_lo(v3.z)
              + bf2f_lo(v4.z) + bf2f_lo(v5.z) + bf2f_lo(v6.z) + bf2f_lo(v7.z);
        a[5] += bf2f_hi(v0.z) + bf2f_hi(v1.z) + bf2f_hi(v2.z) + bf2f_hi(v3.z)
              + bf2f_hi(v4.z) + bf2f_hi(v5.z) + bf2f_hi(v6.z) + bf2f_hi(v7.z);
        a[6] += bf2f_lo(v0.w) + bf2f_lo(v1.w) + bf2f_lo(v2.w) + bf2f_lo(v3.w)
              + bf2f_lo(v4.w) + bf2f_lo(v5.w) + bf2f_lo(v6.w) + bf2f_lo(v7.w);
        a[7] += bf2f_hi(v0.w) + bf2f_hi(v1.w) + bf2f_hi(v2.w) + bf2f_hi(v3.w)
              + bf2f_hi(v4.w) + bf2f_hi(v5.w) + bf2f_hi(v6.w) + bf2f_hi(v7.w);
    }
    for (; i < e1; ++i) {
        uint4 v = base[(size_t)ebuf[i] * 64 + lane];
        a[0] += bf2f_lo(v.x); a[1] += bf2f_hi(v.x);
        a[2] += bf2f_lo(v.y); a[3] += bf2f_hi(v.y);
        a[4] += bf2f_lo(v.z); a[5] += bf2f_hi(v.z);
        a[6] += bf2f_lo(v.w); a[7] += bf2f_hi(v.w);
    }
    float inv = 1.0f / fmaxf((float)(e1 - e0), 1.0f);
    uint4 o;
    o.x = f2bf(a[0] * inv) | (f2bf(a[1] * inv) << 16);
    o.y = f2bf(a[2] * inv) | (f2bf(a[3] * inv) << 16);
    o.z = f2bf(a[4] * inv) | (f2bf(a[5] * inv) << 16);
    o.w = f2bf(a[6] * inv) | (f2bf(a[7] * inv) << 16);
    ((uint4*)outb)[(size_t)w * 64 + lane] = o;
}

// ---------------- bf16 MFMA GEMM (R12-exact: BK=32, XCD swizzle) -----------
// Retained for layer 1 (K=256). T2 is measured-NULL on 2-phase structures.
__global__ __launch_bounds__(256) void gemm_mfma(
    const unsigned short* __restrict__ A0,   // [N, K0] bf16
    const unsigned short* __restrict__ A1,   // [N, K1] bf16, K1 == K0
    const unsigned short* __restrict__ W,    // [C, K0+K1] bf16 row-major
    const float* __restrict__ b,             // [C] fp32
    unsigned short* __restrict__ outb,       // [N, C] bf16 (mode 0)
    const float* __restrict__ Wo,            // [C] fp32    (mode 1)
    float* __restrict__ logit,               // [N] fp32    (mode 1)
    int N, int K0, int K1, int C, int mode)
{
    // --- XCD-aware decode ---
    const int nrow = (N + 127) >> 7;
    const int id   = blockIdx.x;
    const int rowb = ((id >> 5) << 3) + (id & 7);   // rslot*8 + xcd
    const int colb = (id >> 3) & 3;
    if (rowb >= nrow) return;

    const int K = K0 + K1;
    const int S = K0;               // row stride of both A0 and A1
    __shared__ short As[2][4096];   // [128][32] per buffer, 8 KB
    __shared__ short Bs[2][4096];

    const int tid  = threadIdx.x;
    const int lane = tid & 63;
    const int wave = tid >> 6;
    const int wm = wave & 1, wn = wave >> 1;
    const int cl = lane & 15, quad = lane >> 4;
    const int row0 = rowb * 128;
    const int col0 = colb * 128;

    // staging: lane = 4r+j; wave w, load i covers tile rows w*32+i*16 .. +16
    const int r = lane >> 2;        // 0..15
    const int j = lane & 3;         // 16B chunk within the row's 64B K-slice
    const int trow0 = wave * 32 + r;
    const int trow1 = trow0 + 16;
    // clamp OOB tile rows to N-1 (loaded garbage discarded by epilogue guard)
    const int ar0 = (row0 + trow0 < N) ? row0 + trow0 : N - 1;
    const int ar1 = (row0 + trow1 < N) ? row0 + trow1 : N - 1;
    const size_t aoff0 = (size_t)ar0 * S + j * 8;
    const size_t aoff1 = (size_t)ar1 * S + j * 8;
    const size_t boff0 = (size_t)(col0 + trow0) * K + j * 8;
    const size_t boff1 = (size_t)(col0 + trow1) * K + j * 8;
    const int lds0 = (wave * 32) * 32;        // shorts; wave-uniform
    const int lds1 = (wave * 32 + 16) * 32;

    f32x4 acc[4][4];
    #pragma unroll
    for (int mt = 0; mt < 4; ++mt)
        #pragma unroll
        for (int nt = 0; nt < 4; ++nt)
            acc[mt][nt] = (f32x4){0.f, 0.f, 0.f, 0.f};

    // prologue: DMA tile 0 into buffer 0
    GLOAD_LDS16(A0 + aoff0, &As[0][lds0]);
    GLOAD_LDS16(A0 + aoff1, &As[0][lds1]);
    GLOAD_LDS16(W  + boff0, &Bs[0][lds0]);
    GLOAD_LDS16(W  + boff1, &Bs[0][lds1]);

    const int iters = K >> 5;
    for (int i = 0; i < iters; ++i) {
        const int cur = i & 1;
        // barrier drains tile i's DMA (vmcnt0) and fences tile i-1 frag reads
        __syncthreads();
        if (i + 1 < iters) {
            const int kn = (i + 1) << 5;
            const unsigned short* Ab = (kn < K0) ? (A0 + kn) : (A1 + (kn - K0));
            const unsigned short* Wb = W + kn;
            const int nb = cur ^ 1;
            GLOAD_LDS16(Ab + aoff0, &As[nb][lds0]);
            GLOAD_LDS16(Ab + aoff1, &As[nb][lds1]);
            GLOAD_LDS16(Wb + boff0, &Bs[nb][lds0]);
            GLOAD_LDS16(Wb + boff1, &Bs[nb][lds1]);
        }

        bf16x8 af[4], bfr[4];
        #pragma unroll
        for (int mt = 0; mt < 4; ++mt)
            af[mt] = *(const bf16x8*)&As[cur][(wm * 64 + mt * 16 + cl) * 32 + quad * 8];
        #pragma unroll
        for (int nt = 0; nt < 4; ++nt)
            bfr[nt] = *(const bf16x8*)&Bs[cur][(wn * 64 + nt * 16 + cl) * 32 + quad * 8];

        #pragma unroll
        for (int mt = 0; mt < 4; ++mt)
            #pragma unroll
            for (int nt = 0; nt < 4; ++nt)
                acc[mt][nt] = __builtin_amdgcn_mfma_f32_16x16x32_bf16(
                    af[mt], bfr[nt], acc[mt][nt], 0, 0, 0);
    }

    if (mode == 0) {
        #pragma unroll
        for (int nt = 0; nt < 4; ++nt) {
            const int colx = col0 + wn * 64 + nt * 16 + cl;
            const float bb = b[colx];
            #pragma unroll
            for (int mt = 0; mt < 4; ++mt) {
                #pragma unroll
                for (int rr = 0; rr < 4; ++rr) {
                    int row = row0 + wm * 64 + mt * 16 + quad * 4 + rr;
                    if (row < N)
                        outb[(size_t)row * C + colx] =
                            (unsigned short)f2bf(fmaxf(acc[mt][nt][rr] + bb, 0.0f));
                }
            }
        }
    } else {
        float bv[4], wv2[4];
        #pragma unroll
        for (int nt = 0; nt < 4; ++nt) {
            const int colx = col0 + wn * 64 + nt * 16 + cl;
            bv[nt] = b[colx];
            wv2[nt] = Wo[colx];
        }
        #pragma unroll
        for (int mt = 0; mt < 4; ++mt) {
            #pragma unroll
            for (int rr = 0; rr < 4; ++rr) {
                float s = 0.0f;
                #pragma unroll
                for (int nt = 0; nt < 4; ++nt)
                    s += fmaxf(acc[mt][nt][rr] + bv[nt], 0.0f) * wv2[nt];
                s += __shfl_xor(s, 1);
                s += __shfl_xor(s, 2);
                s += __shfl_xor(s, 4);
                s += __shfl_xor(s, 8);
                int row = row0 + wm * 64 + mt * 16 + quad * 4 + rr;
                if (cl == 0 && row < N) atomicAdd(&logit[row], s);
            }
        }
    }
}

// ---------------- layer-2: 256x256-tile 8-phase GEMM + fused head ----------
// C = relu([A0|A1] @ W^T + b); logit[row] += sum_col C[row,col]*Wo[col].
// Fixed shape: A row stride 512 (K0=K1=512, K=1024), W [512][1024].
// 512 thr = 8 waves (2Mx4N); wave tile 128x64; BK=64; 2 K-tiles per iter,
// 8 phases per iter, 16 MFMA per phase, ONE barrier per phase (R19).
// LDS 128 KiB (2 dbuf x (A 32K + B 32K)).
// Hazard proof for single barrier: MFMA reads registers only; each wave's
// ds_reads complete before its MFMA issues (compiler lgkmcnt); so the
// phase-open barrier orders {all waves' phase-p reads} before {phase-p+1+
// DMA overwrites}. vmcnt gates precede a phase-open barrier -> all-waves
// join publishes DMA completion to the dependent reads after it.

#define KT2  16   // K-tiles of 64 (K = 1024)
#define NIT2 8    // iterations (2 K-tiles each)

#define STG_A(hh, kt, buf) do {                                                        \
    const unsigned short* _pA = ((kt) < 8) ? A0 : A1;                                  \
    const size_t _ko = (size_t)(((kt) & 7) << 6);                                      \
    GLOAD_LDS16(_pA + _ko + offA[hh][0],                                               \
                lds + (buf) * 65536 + (hh) * 16384 + (w * 2 + 0) * 1024);              \
    GLOAD_LDS16(_pA + _ko + offA[hh][1],                                               \
                lds + (buf) * 65536 + (hh) * 16384 + (w * 2 + 1) * 1024);              \
} while (0)

#define STG_B(hh, kt, buf) do {                                                        \
    const size_t _ko = (size_t)((kt) << 6);                                            \
    GLOAD_LDS16(W + _ko + offB[hh][0],                                                 \
                lds + (buf) * 65536 + 32768 + (hh) * 16384 + (w * 2 + 0) * 1024);      \
    GLOAD_LDS16(W + _ko + offB[hh][1],                                                 \
                lds + (buf) * 65536 + 32768 + (hh) * 16384 + (w * 2 + 1) * 1024);      \
} while (0)

#define RD_A8(qm, buf) do {                                                            \
    _Pragma("unroll")                                                                  \
    for (int _m = 0; _m < 4; ++_m) {                                                   \
        af[_m][0] = *(const bf16x8*)(lds + (buf) * 65536 +                             \
                    ((aBase + ((qm) * 4 + _m) * 2048) ^ swz));                         \
        af[_m][1] = *(const bf16x8*)(lds + (buf) * 65536 +                             \
                    ((aBase + ((qm) * 4 + _m) * 2048 + 64) ^ swz));                    \
    }                                                                                  \
} while (0)

#define RD_B4(qn, buf) do {                                                            \
    _Pragma("unroll")                                                                  \
    for (int _n = 0; _n < 2; ++_n) {                                                   \
        bq[(qn) * 2 + _n][0] = *(const bf16x8*)(lds + (buf) * 65536 +                  \
                    ((bBase + ((qn) * 2 + _n) * 2048) ^ swz));                         \
        bq[(qn) * 2 + _n][1] = *(const bf16x8*)(lds + (buf) * 65536 +                  \
                    ((bBase + ((qn) * 2 + _n) * 2048 + 64) ^ swz));                    \
    }                                                                                  \
} while (0)

#define MFMA16(qm, qn) do {                                                            \
    _Pragma("unroll")                                                                  \
    for (int _kk = 0; _kk < 2; ++_kk)                                                  \
        _Pragma("unroll")                                                              \
        for (int _m = 0; _m < 4; ++_m)                                                 \
            _Pragma("unroll")                                                          \
            for (int _n = 0; _n < 2; ++_n)                                             \
                acc[(qm) * 4 + _m][(qn) * 2 + _n] =                                    \
                    __builtin_amdgcn_mfma_f32_16x16x32_bf16(                           \
                        af[_m][_kk], bq[(qn) * 2 + _n][_kk],                           \
                        acc[(qm) * 4 + _m][(qn) * 2 + _n], 0, 0, 0);                   \
} while (0)

// phase-open: one barrier; sched_barrier(0) on both sides pins memory ops
#define PH_OPEN() do {                                                                 \
    __builtin_amdgcn_sched_barrier(0);                                                 \
    __builtin_amdgcn_s_barrier();                                                      \
    __builtin_amdgcn_sched_barrier(0);                                                 \
} while (0)

#define PH_MFMA(qm, qn) do {                                                           \
    __builtin_amdgcn_s_setprio(1);                                                     \
    MFMA16(qm, qn);                                                                    \
    __builtin_amdgcn_s_setprio(0);                                                     \
} while (0)

__global__ __launch_bounds__(512, 2) void gemm2_8ph(
    const unsigned short* __restrict__ A0,   // h1b [N,512] bf16
    const unsigned short* __restrict__ A1,   // n2b [N,512] bf16
    const unsigned short* __restrict__ W,    // W2b [512,1024] bf16
    const float* __restrict__ b,             // b2 [512]
    const float* __restrict__ Wo,            // [512]
    float* __restrict__ logit,               // [N]
    int N)
{
    __shared__ char lds[131072];             // 2 dbuf x (A 32K | B 32K)

    // XCD-aware swizzle: col siblings of a row-tile on one XCD (A L2-reuse)
    const int nrt = (N + 255) >> 8;
    const int nb  = nrt * 2;
    const int orig = blockIdx.x;
    int virt = orig;
    if ((nb & 7) == 0) virt = (orig & 7) * (nb >> 3) + (orig >> 3);
    const int row0 = (virt >> 1) << 8;
    const int col0 = (virt & 1) << 8;

    const int tid = threadIdx.x;
    const int w = tid >> 6, l = tid & 63;
    const int wr = w >> 2, wc = w & 3;       // 2x4 wave grid
    const int cl = l & 15, quad = l >> 4;

    // ---- staging addresses (inverse-swizzled global source; linear dest) ----
    // dest byte t = hh*16384 + (w*2+i)*1024 + l*16  ->  row = (w*2+i)*8+(l>>3),
    // phys col = (l&7)*16 B. Need col_log = col_phys ^ ((row&7)<<4), row&7=l>>3:
    // c_log = 16*((l&7) ^ (l>>3)) bytes = 8*((l&7)^(l>>3)) elements.
    const int c_log = ((l & 7) ^ (l >> 3)) * 8;
    size_t offA[2][2], offB[2][2];
    #pragma unroll
    for (int hh = 0; hh < 2; ++hh)
        #pragma unroll
        for (int i = 0; i < 2; ++i) {
            int ra = row0 + hh * 128 + (w * 2 + i) * 8 + (l >> 3);
            if (ra > N - 1) ra = N - 1;      // clamp; epilogue guards row<N
            offA[hh][i] = (size_t)ra * 512 + c_log;
            const int rb = col0 + hh * 128 + (w * 2 + i) * 8 + (l >> 3);
            offB[hh][i] = (size_t)rb * 1024 + c_log;
        }

    // ---- ds_read: phys = logical ^ ((row&7)<<4); row&7 = cl&7 for both A,B
    const int swz   = (cl & 7) << 4;
    const int aBase = wr * 16384 + cl * 128 + quad * 16;           // + mt*2048 + kk*64
    const int bBase = 32768 + (wc * 64 + cl) * 128 + quad * 16;    // + nt*2048 + kk*64

    f32x4 acc[8][4];
    #pragma unroll
    for (int mt = 0; mt < 8; ++mt)
        #pragma unroll
        for (int nt = 0; nt < 4; ++nt)
            acc[mt][nt] = (f32x4){0.f, 0.f, 0.f, 0.f};

    bf16x8 af[4][2];     // A frags of current qm group
    bf16x8 bq[4][2];     // all B frags of current K-tile

    // ---- prologue: t0 fully (8 instr), then B(t1) (4 instr) ----
    STG_A(0, 0, 0); STG_A(1, 0, 0);
    STG_B(0, 0, 0); STG_B(1, 0, 0);
    STG_B(0, 1, 1); STG_B(1, 1, 1);
    asm volatile("s_waitcnt vmcnt(4)" ::: "memory");   // t0 landed; B(t1) may fly

    for (int j = 0; j < NIT2; ++j) {
        const int t1 = 2 * j + 1;
        const int t2 = (2 * j + 2 < KT2) ? 2 * j + 2 : KT2 - 2;  // clamped, even
        const int t3 = (2 * j + 3 < KT2) ? 2 * j + 3 : KT2 - 1;  // clamped, odd
        // ---- K-tile t0 = 2j (buf0) ----
        PH_OPEN();                                // joins prologue gate / p7 gate
        RD_A8(0, 0); RD_B4(0, 0);
        STG_A(0, t1, 1);                          // overwrites A(t1-2), last read prev p6
        PH_MFMA(0, 0);                            // p0
        PH_OPEN();
        RD_B4(1, 0);
        STG_A(1, t1, 1);
        PH_MFMA(0, 1);                            // p1
        PH_OPEN();
        RD_A8(1, 0);
        STG_B(0, t2, 0);                          // overwrites B(t0), last read p1
        PH_MFMA(1, 1);                            // p2
        PH_OPEN();
        STG_B(1, t2, 0);
        asm volatile("s_waitcnt vmcnt(4)" ::: "memory");   // GATE t1: A@p0,p1 landed
        PH_MFMA(1, 0);                            // p3
        // ---- K-tile t1 = 2j+1 (buf1) ----
        PH_OPEN();                                // publishes gate to p4 readers
        RD_A8(0, 1); RD_B4(0, 1);
        STG_A(0, t2, 0);                          // overwrites A(t0), last read p2
        PH_MFMA(0, 0);                            // p4
        PH_OPEN();
        RD_B4(1, 1);
        STG_A(1, t2, 0);
        PH_MFMA(0, 1);                            // p5
        PH_OPEN();
        RD_A8(1, 1);
        STG_B(0, t3, 1);                          // overwrites B(t1), last read p5
        PH_MFMA(1, 1);                            // p6
        PH_OPEN();
        STG_B(1, t3, 1);
        asm volatile("s_waitcnt vmcnt(4)" ::: "memory");   // GATE t2: B@p2,p3 A@p4,p5
        PH_MFMA(1, 0);                            // p7
    }
    asm volatile("s_waitcnt vmcnt(0)" ::: "memory");   // drain tail stages

    // ---- epilogue: fused ReLU + Wo dot + atomic row add ----
    float bv[4], wv[4];
    #pragma unroll
    for (int nt = 0; nt < 4; ++nt) {
        const int colx = col0 + wc * 64 + nt * 16 + cl;
        bv[nt] = b[colx];
        wv[nt] = Wo[colx];
    }
    #pragma unroll
    for (int mt = 0; mt < 8; ++mt) {
        #pragma unroll
        for (int rr = 0; rr < 4; ++rr) {
            float s = 0.0f;
            #pragma unroll
            for (int nt = 0; nt < 4; ++nt)
                s += fmaxf(acc[mt][nt][rr] + bv[nt], 0.0f) * wv[nt];
            s += __shfl_xor(s, 1);
            s += __shfl_xor(s, 2);
            s += __shfl_xor(s, 4);
            s += __shfl_xor(s, 8);
            const int row = row0 + wr * 128 + mt * 16 + quad * 4 + rr;
            if (cl == 0 && row < N) atomicAdd(&logit[row], s);
        }
    }
}

__global__ void head_kernel(const float* __restrict__ logit, const float* __restrict__ bo,
                            float* __restrict__ out, int N) {
    int i = blockIdx.x * 256 + threadIdx.x;
    if (i < N) out[i] = 1.0f / (1.0f + expf(-(logit[i] + bo[0])));
}

extern "C" void kernel_launch(void* const* d_in, const int* in_sizes, int n_in,
                              void* d_out, int out_size, void* d_ws, size_t ws_size,
                              hipStream_t stream) {
    const float* x  = (const float*)d_in[0];
    const int*   ei = (const int*)d_in[1];
    const float* W1 = (const float*)d_in[2];
    const float* b1 = (const float*)d_in[3];
    const float* W2 = (const float*)d_in[4];
    const float* b2 = (const float*)d_in[5];
    const float* Wo = (const float*)d_in[6];
    const float* bo = (const float*)d_in[7];
    float* out = (float*)d_out;

    const int N = in_sizes[0] / 128;   // 50000
    const int E = in_sizes[1] / 2;     // 400000
    const int* src = ei;
    const int* dst = ei + E;

    char* ws = (char*)d_ws;
    size_t off = 0;
    auto alloc = [&](size_t bytes) {
        void* p = ws + off;
        off += (bytes + 255) & ~(size_t)255;
        return p;
    };
    int* deg      = (int*)alloc((size_t)N * 4);
    int* rowstart = (int*)alloc((size_t)(N + 1) * 4);
    int* cursor   = (int*)alloc((size_t)N * 4);
    int* partial  = (int*)alloc((size_t)64 * 4);
    int* ebuf     = (int*)alloc((size_t)E * 4);
    float* logit  = (float*)alloc((size_t)N * 4);
    unsigned short* xb  = (unsigned short*)alloc((size_t)N * 128 * 2);
    unsigned short* W1b = (unsigned short*)alloc((size_t)512 * 256 * 2);
    unsigned short* W2b = (unsigned short*)alloc((size_t)512 * 1024 * 2);
    unsigned short* n1b = (unsigned short*)alloc((size_t)N * 128 * 2);
    unsigned short* h1b = (unsigned short*)alloc((size_t)N * 512 * 2);
    unsigned short* n2b = (unsigned short*)alloc((size_t)N * 512 * 2);
    (void)ws_size; (void)n_in; (void)out_size;

    hipMemsetAsync(deg,   0, (size_t)N * 4, stream);
    hipMemsetAsync(logit, 0, (size_t)N * 4, stream);

    // fused: cvt x/W1/W2 -> bf16  +  deg histogram (independent DAG roots)
    const int na4 = N * 128 / 4, nb4 = 512 * 256 / 4, nc4 = 512 * 1024 / 4;
    const int cvt_blocks  = ceil_div(na4 + nb4 + nc4, 256);
    const int hist_blocks = ceil_div(E, 256);
    cvt3_hist_kernel<<<cvt_blocks + hist_blocks, 256, 0, stream>>>(
        x, xb, na4, W1, W1b, nb4, W2, W2b, nc4, dst, deg, E, cvt_blocks);

    // CSR build (hierarchical scan)
    const int P = ceil_div(N, 1024);   // 49
    chunk_reduce<<<P, 256, 0, stream>>>(deg, partial, N);
    partial_scan<<<1, 64, 0, stream>>>(partial, rowstart + N, P);
    chunk_scan<<<P, 256, 0, stream>>>(deg, partial, rowstart, cursor, N);
    bucket_kernel<<<ceil_div(E, 256), 256, 0, stream>>>(src, dst, cursor, ebuf, E);

    // layer 1: 128^2-tile kernel (K=256, small) — XCD-swizzled 1D grid
    const int nrow = ceil_div(N, 128);              // 391
    const int gblocks = ceil_div(nrow, 8) * 8 * 4;  // 1568
    gather_mean_128<<<ceil_div(N * 64, 256), 256, 0, stream>>>(rowstart, ebuf,
                                                               (const unsigned*)xb, (unsigned*)n1b, N);
    gemm_mfma<<<gblocks, 256, 0, stream>>>(xb, n1b, W1b, b1, h1b, nullptr, nullptr,
                                           N, 128, 128, 512, 0);

    // layer 2 + fused head: 256^2-tile 8-phase kernel
    gather_mean_512<<<ceil_div(N * 64, 256), 256, 0, stream>>>(rowstart, ebuf, h1b, n2b, N);
    const int nrt2 = ceil_div(N, 256);              // 196 -> 392 blocks
    gemm2_8ph<<<nrt2 * 2, 512, 0, stream>>>(h1b, n2b, W2b, b2, Wo, logit, N);

    head_kernel<<<ceil_div(N, 256), 256, 0, stream>>>(logit, bo, out, N);
}

// Round 4
// 335.549 us; speedup vs baseline: 1.0444x; 1.0061x over previous
//
#include <hip/hip_runtime.h>
#include <math.h>

// ---------------------------------------------------------------------------
// GraphSAGE fraud detector. CSR-gather aggregation + bf16 MFMA GEMMs.
// R20: layer-2 GEMM rebuilt as 128x256-tile / 8 waves of 64x64 / BK=32 /
// TRIPLE-buffered LDS (72 KB) / 2 blocks per CU. R19 post-mortem arithmetic:
// (a) old structure's LDS traffic (256KB/K-tile: A-frags x4 col-waves) capped
// MfmaUtil at ~60%; (b) block-wide vmcnt gates + barriers at 1 block/CU
// exposed full memory latency (no co-resident block to cover). New design:
// acc 64 regs/wave -> 4 waves/SIMD, 72KB LDS -> 2 blocks/CU (TLP covers
// gates); per-K-tile LDS 88KB ~= MFMA 620cy (balanced); 3-buf gives 2-phase
// prefetch lead with CONSTANT vmcnt(3) gate (never drains, T4). Gate sits
// BEFORE the phase barrier (join publishes DMA completion). Stage(t+2) hits
// buf((t+2)%3) = buffer read in ph(t-1); those reads retired before each
// wave's own MFMA -> 1-barrier separation safe.
// T2 swizzle for 64B rows: phys = logical ^ (((row>>1)&3)<<4) -> even
// 8-access/bank (same minimal distribution as R18's zero-conflict scheme).
// Inverse-swizzled global source c_log = 8*((l&3)^((l>>3)&3)); read swz =
// ((cl>>1)&3)<<4. Bijective m204 XCD swizzle (782 blocks).
// MFMA 16x16x32 bf16: A-frag A[m=lane&15][k=quad*8+j]; C/D col=lane&15,
// row=quad*4+reg (m89/m97-verified layouts).
// ---------------------------------------------------------------------------

typedef __attribute__((ext_vector_type(8))) short bf16x8;   // 8 bf16, 4 VGPRs
typedef __attribute__((ext_vector_type(4))) float f32x4;

static inline int ceil_div(int a, int b) { return (a + b - 1) / b; }

__device__ inline float bf2f_lo(unsigned u) { return __builtin_bit_cast(float, u << 16); }
__device__ inline float bf2f_hi(unsigned u) { return __builtin_bit_cast(float, u & 0xffff0000u); }
__device__ inline unsigned f2bf(float f) {   // RNE round to bf16, bits in low 16
    unsigned u = __builtin_bit_cast(unsigned, f);
    u += 0x7fffu + ((u >> 16) & 1u);
    return u >> 16;
}

// async global->LDS, 16 B per lane; LDS dest = wave-uniform base + lane*16
#define GLOAD_LDS16(gp, lp)                                                   \
    __builtin_amdgcn_global_load_lds(                                         \
        (__attribute__((address_space(1))) void*)(gp),                        \
        (__attribute__((address_space(3))) void*)(lp), 16, 0, 0)

// ---------------- fused cvt(x,W1,W2) + deg histogram ----------------

__global__ void cvt3_hist_kernel(const float* __restrict__ a, unsigned short* __restrict__ ao, int na4,
                                 const float* __restrict__ b, unsigned short* __restrict__ bo, int nb4,
                                 const float* __restrict__ c, unsigned short* __restrict__ co, int nc4,
                                 const int* __restrict__ dst, int* __restrict__ deg, int E,
                                 int cvt_blocks) {
    if ((int)blockIdx.x < cvt_blocks) {
        int i = blockIdx.x * 256 + threadIdx.x;
        const float* in; unsigned short* out; int k;
        if (i < na4)                  { in = a; out = ao; k = i; }
        else if (i < na4 + nb4)       { in = b; out = bo; k = i - na4; }
        else if (i < na4 + nb4 + nc4) { in = c; out = co; k = i - na4 - nb4; }
        else return;
        float4 v = ((const float4*)in)[k];
        ushort4 o;
        o.x = (unsigned short)f2bf(v.x);
        o.y = (unsigned short)f2bf(v.y);
        o.z = (unsigned short)f2bf(v.z);
        o.w = (unsigned short)f2bf(v.w);
        ((ushort4*)out)[k] = o;
    } else {
        int e = (blockIdx.x - cvt_blocks) * 256 + threadIdx.x;
        if (e < E) atomicAdd(&deg[dst[e]], 1);
    }
}

// ---------------- CSR build ----------------

// per-1024-chunk sums
__global__ __launch_bounds__(256) void chunk_reduce(const int* __restrict__ deg,
                                                    int* __restrict__ partial, int N) {
    int base = blockIdx.x * 1024;
    int s = 0;
    for (int i = threadIdx.x; i < 1024; i += 256) {
        int idx = base + i;
        if (idx < N) s += deg[idx];
    }
    #pragma unroll
    for (int off = 32; off; off >>= 1) s += __shfl_down(s, off);
    __shared__ int ws[4];
    if ((threadIdx.x & 63) == 0) ws[threadIdx.x >> 6] = s;
    __syncthreads();
    if (threadIdx.x == 0) partial[blockIdx.x] = ws[0] + ws[1] + ws[2] + ws[3];
}

// exclusive scan of P<=64 partials (one wave); writes rowstart[N]=total
__global__ void partial_scan(int* __restrict__ partial, int* __restrict__ rowstartN, int P) {
    int lane = threadIdx.x;
    int v = (lane < P) ? partial[lane] : 0;
    int incl = v;
    #pragma unroll
    for (int off = 1; off < 64; off <<= 1) {
        int t = __shfl_up(incl, off);
        if (lane >= off) incl += t;
    }
    if (lane < P) partial[lane] = incl - v;
    if (lane == 63) *rowstartN = incl;
}

// per-chunk exclusive scan + global offset; writes rowstart and cursor
__global__ __launch_bounds__(256) void chunk_scan(const int* __restrict__ deg,
                                                  const int* __restrict__ partial,
                                                  int* __restrict__ rowstart,
                                                  int* __restrict__ cursor, int N) {
    int base = blockIdx.x * 1024 + threadIdx.x * 4;
    int v[4];
    #pragma unroll
    for (int j = 0; j < 4; ++j) {
        int i = base + j;
        v[j] = (i < N) ? deg[i] : 0;
    }
    int mysum = v[0] + v[1] + v[2] + v[3];
    int incl = mysum;
    int lane = threadIdx.x & 63, wave = threadIdx.x >> 6;
    #pragma unroll
    for (int off = 1; off < 64; off <<= 1) {
        int t = __shfl_up(incl, off);
        if (lane >= off) incl += t;
    }
    __shared__ int ws[4];
    if (lane == 63) ws[wave] = incl;
    __syncthreads();
    int run = partial[blockIdx.x] + incl - mysum;
    for (int w = 0; w < wave; ++w) run += ws[w];
    #pragma unroll
    for (int j = 0; j < 4; ++j) {
        int i = base + j;
        if (i < N) { rowstart[i] = run; cursor[i] = run; }
        run += v[j];
    }
}

__global__ void bucket_kernel(const int* __restrict__ src, const int* __restrict__ dst,
                              int* __restrict__ cursor, int* __restrict__ ebuf, int E) {
    int e = blockIdx.x * 256 + threadIdx.x;
    if (e < E) {
        int pos = atomicAdd(&cursor[dst[e]], 1);
        ebuf[pos] = src[e];
    }
}

// ---------------- gather means ----------------

// one wave per dst row; bf16 xb [N,128] -> bf16 mean [N,128]; fp32 accum
__global__ void gather_mean_128(const int* __restrict__ rowstart, const int* __restrict__ ebuf,
                                const unsigned* __restrict__ featb, unsigned* __restrict__ outb, int N) {
    int w = (blockIdx.x * blockDim.x + threadIdx.x) >> 6;
    int lane = threadIdx.x & 63;
    if (w >= N) return;
    int e0 = rowstart[w], e1 = rowstart[w + 1];
    float ax = 0.0f, ay = 0.0f;
    int i = e0;
    for (; i + 8 <= e1; i += 8) {           // 8-edge unroll for MLP
        unsigned v0 = featb[(size_t)ebuf[i]     * 64 + lane];
        unsigned v1 = featb[(size_t)ebuf[i + 1] * 64 + lane];
        unsigned v2 = featb[(size_t)ebuf[i + 2] * 64 + lane];
        unsigned v3 = featb[(size_t)ebuf[i + 3] * 64 + lane];
        unsigned v4 = featb[(size_t)ebuf[i + 4] * 64 + lane];
        unsigned v5 = featb[(size_t)ebuf[i + 5] * 64 + lane];
        unsigned v6 = featb[(size_t)ebuf[i + 6] * 64 + lane];
        unsigned v7 = featb[(size_t)ebuf[i + 7] * 64 + lane];
        ax += bf2f_lo(v0) + bf2f_lo(v1) + bf2f_lo(v2) + bf2f_lo(v3)
            + bf2f_lo(v4) + bf2f_lo(v5) + bf2f_lo(v6) + bf2f_lo(v7);
        ay += bf2f_hi(v0) + bf2f_hi(v1) + bf2f_hi(v2) + bf2f_hi(v3)
            + bf2f_hi(v4) + bf2f_hi(v5) + bf2f_hi(v6) + bf2f_hi(v7);
    }
    for (; i < e1; ++i) {
        unsigned v = featb[(size_t)ebuf[i] * 64 + lane];
        ax += bf2f_lo(v); ay += bf2f_hi(v);
    }
    float inv = 1.0f / fmaxf((float)(e1 - e0), 1.0f);
    outb[(size_t)w * 64 + lane] = f2bf(ax * inv) | (f2bf(ay * inv) << 16);
}

// one wave per dst row; bf16 feat [N,512] -> bf16 mean [N,512]; fp32 accum
__global__ void gather_mean_512(const int* __restrict__ rowstart, const int* __restrict__ ebuf,
                                const unsigned short* __restrict__ featb,
                                unsigned short* __restrict__ outb, int N) {
    int w = (blockIdx.x * blockDim.x + threadIdx.x) >> 6;
    int lane = threadIdx.x & 63;
    if (w >= N) return;
    int e0 = rowstart[w], e1 = rowstart[w + 1];
    float a[8] = {0, 0, 0, 0, 0, 0, 0, 0};
    const uint4* base = (const uint4*)featb;     // 512 bf16/row = 64 uint4/row
    int i = e0;
    for (; i + 8 <= e1; i += 8) {           // 8-edge unroll for MLP
        uint4 v0 = base[(size_t)ebuf[i]     * 64 + lane];
        uint4 v1 = base[(size_t)ebuf[i + 1] * 64 + lane];
        uint4 v2 = base[(size_t)ebuf[i + 2] * 64 + lane];
        uint4 v3 = base[(size_t)ebuf[i + 3] * 64 + lane];
        uint4 v4 = base[(size_t)ebuf[i + 4] * 64 + lane];
        uint4 v5 = base[(size_t)ebuf[i + 5] * 64 + lane];
        uint4 v6 = base[(size_t)ebuf[i + 6] * 64 + lane];
        uint4 v7 = base[(size_t)ebuf[i + 7] * 64 + lane];
        a[0] += bf2f_lo(v0.x) + bf2f_lo(v1.x) + bf2f_lo(v2.x) + bf2f_lo(v3.x)
              + bf2f_lo(v4.x) + bf2f_lo(v5.x) + bf2f_lo(v6.x) + bf2f_lo(v7.x);
        a[1] += bf2f_hi(v0.x) + bf2f_hi(v1.x) + bf2f_hi(v2.x) + bf2f_hi(v3.x)
              + bf2f_hi(v4.x) + bf2f_hi(v5.x) + bf2f_hi(v6.x) + bf2f_hi(v7.x);
        a[2] += bf2f_lo(v0.y) + bf2f_lo(v1.y) + bf2f_lo(v2.y) + bf2f_lo(v3.y)
              + bf2f_lo(v4.y) + bf2f_lo(v5.y) + bf2f_lo(v6.y) + bf2f_lo(v7.y);
        a[3] += bf2f_hi(v0.y) + bf2f_hi(v1.y) + bf2f_hi(v2.y) + bf2f_hi(v3.y)
              + bf2f_hi(v4.y) + bf2f_hi(v5.y) + bf2f_hi(v6.y) + bf2f_hi(v7.y);
        a[4] += bf2f_lo(v0.z) + bf2f_lo(v1.z) + bf2f_lo(v2.z) + bf2f_lo(v3.z)
              + bf2f_lo(v4.z) + bf2f_lo(v5.z) + bf2f_lo(v6.z) + bf2f_lo(v7.z);
        a[5] += bf2f_hi(v0.z) + bf2f_hi(v1.z) + bf2f_hi(v2.z) + bf2f_hi(v3.z)
              + bf2f_hi(v4.z) + bf2f_hi(v5.z) + bf2f_hi(v6.z) + bf2f_hi(v7.z);
        a[6] += bf2f_lo(v0.w) + bf2f_lo(v1.w) + bf2f_lo(v2.w) + bf2f_lo(v3.w)
              + bf2f_lo(v4.w) + bf2f_lo(v5.w) + bf2f_lo(v6.w) + bf2f_lo(v7.w);
        a[7] += bf2f_hi(v0.w) + bf2f_hi(v1.w) + bf2f_hi(v2.w) + bf2f_hi(v3.w)
              + bf2f_hi(v4.w) + bf2f_hi(v5.w) + bf2f_hi(v6.w) + bf2f_hi(v7.w);
    }
    for (; i < e1; ++i) {
        uint4 v = base[(size_t)ebuf[i] * 64 + lane];
        a[0] += bf2f_lo(v.x); a[1] += bf2f_hi(v.x);
        a[2] += bf2f_lo(v.y); a[3] += bf2f_hi(v.y);
        a[4] += bf2f_lo(v.z); a[5] += bf2f_hi(v.z);
        a[6] += bf2f_lo(v.w); a[7] += bf2f_hi(v.w);
    }
    float inv = 1.0f / fmaxf((float)(e1 - e0), 1.0f);
    uint4 o;
    o.x = f2bf(a[0] * inv) | (f2bf(a[1] * inv) << 16);
    o.y = f2bf(a[2] * inv) | (f2bf(a[3] * inv) << 16);
    o.z = f2bf(a[4] * inv) | (f2bf(a[5] * inv) << 16);
    o.w = f2bf(a[6] * inv) | (f2bf(a[7] * inv) << 16);
    ((uint4*)outb)[(size_t)w * 64 + lane] = o;
}

// ---------------- bf16 MFMA GEMM (R12-exact: BK=32, XCD swizzle) -----------
// Retained for layer 1 (K=256).
__global__ __launch_bounds__(256) void gemm_mfma(
    const unsigned short* __restrict__ A0,   // [N, K0] bf16
    const unsigned short* __restrict__ A1,   // [N, K1] bf16, K1 == K0
    const unsigned short* __restrict__ W,    // [C, K0+K1] bf16 row-major
    const float* __restrict__ b,             // [C] fp32
    unsigned short* __restrict__ outb,       // [N, C] bf16 (mode 0)
    const float* __restrict__ Wo,            // [C] fp32    (mode 1)
    float* __restrict__ logit,               // [N] fp32    (mode 1)
    int N, int K0, int K1, int C, int mode)
{
    // --- XCD-aware decode ---
    const int nrow = (N + 127) >> 7;
    const int id   = blockIdx.x;
    const int rowb = ((id >> 5) << 3) + (id & 7);   // rslot*8 + xcd
    const int colb = (id >> 3) & 3;
    if (rowb >= nrow) return;

    const int K = K0 + K1;
    const int S = K0;               // row stride of both A0 and A1
    __shared__ short As[2][4096];   // [128][32] per buffer, 8 KB
    __shared__ short Bs[2][4096];

    const int tid  = threadIdx.x;
    const int lane = tid & 63;
    const int wave = tid >> 6;
    const int wm = wave & 1, wn = wave >> 1;
    const int cl = lane & 15, quad = lane >> 4;
    const int row0 = rowb * 128;
    const int col0 = colb * 128;

    // staging: lane = 4r+j; wave w, load i covers tile rows w*32+i*16 .. +16
    const int r = lane >> 2;        // 0..15
    const int j = lane & 3;         // 16B chunk within the row's 64B K-slice
    const int trow0 = wave * 32 + r;
    const int trow1 = trow0 + 16;
    // clamp OOB tile rows to N-1 (loaded garbage discarded by epilogue guard)
    const int ar0 = (row0 + trow0 < N) ? row0 + trow0 : N - 1;
    const int ar1 = (row0 + trow1 < N) ? row0 + trow1 : N - 1;
    const size_t aoff0 = (size_t)ar0 * S + j * 8;
    const size_t aoff1 = (size_t)ar1 * S + j * 8;
    const size_t boff0 = (size_t)(col0 + trow0) * K + j * 8;
    const size_t boff1 = (size_t)(col0 + trow1) * K + j * 8;
    const int lds0 = (wave * 32) * 32;        // shorts; wave-uniform
    const int lds1 = (wave * 32 + 16) * 32;

    f32x4 acc[4][4];
    #pragma unroll
    for (int mt = 0; mt < 4; ++mt)
        #pragma unroll
        for (int nt = 0; nt < 4; ++nt)
            acc[mt][nt] = (f32x4){0.f, 0.f, 0.f, 0.f};

    // prologue: DMA tile 0 into buffer 0
    GLOAD_LDS16(A0 + aoff0, &As[0][lds0]);
    GLOAD_LDS16(A0 + aoff1, &As[0][lds1]);
    GLOAD_LDS16(W  + boff0, &Bs[0][lds0]);
    GLOAD_LDS16(W  + boff1, &Bs[0][lds1]);

    const int iters = K >> 5;
    for (int i = 0; i < iters; ++i) {
        const int cur = i & 1;
        // barrier drains tile i's DMA (vmcnt0) and fences tile i-1 frag reads
        __syncthreads();
        if (i + 1 < iters) {
            const int kn = (i + 1) << 5;
            const unsigned short* Ab = (kn < K0) ? (A0 + kn) : (A1 + (kn - K0));
            const unsigned short* Wb = W + kn;
            const int nb = cur ^ 1;
            GLOAD_LDS16(Ab + aoff0, &As[nb][lds0]);
            GLOAD_LDS16(Ab + aoff1, &As[nb][lds1]);
            GLOAD_LDS16(Wb + boff0, &Bs[nb][lds0]);
            GLOAD_LDS16(Wb + boff1, &Bs[nb][lds1]);
        }

        bf16x8 af[4], bfr[4];
        #pragma unroll
        for (int mt = 0; mt < 4; ++mt)
            af[mt] = *(const bf16x8*)&As[cur][(wm * 64 + mt * 16 + cl) * 32 + quad * 8];
        #pragma unroll
        for (int nt = 0; nt < 4; ++nt)
            bfr[nt] = *(const bf16x8*)&Bs[cur][(wn * 64 + nt * 16 + cl) * 32 + quad * 8];

        #pragma unroll
        for (int mt = 0; mt < 4; ++mt)
            #pragma unroll
            for (int nt = 0; nt < 4; ++nt)
                acc[mt][nt] = __builtin_amdgcn_mfma_f32_16x16x32_bf16(
                    af[mt], bfr[nt], acc[mt][nt], 0, 0, 0);
    }

    if (mode == 0) {
        #pragma unroll
        for (int nt = 0; nt < 4; ++nt) {
            const int colx = col0 + wn * 64 + nt * 16 + cl;
            const float bb = b[colx];
            #pragma unroll
            for (int mt = 0; mt < 4; ++mt) {
                #pragma unroll
                for (int rr = 0; rr < 4; ++rr) {
                    int row = row0 + wm * 64 + mt * 16 + quad * 4 + rr;
                    if (row < N)
                        outb[(size_t)row * C + colx] =
                            (unsigned short)f2bf(fmaxf(acc[mt][nt][rr] + bb, 0.0f));
                }
            }
        }
    } else {
        float bv[4], wv2[4];
        #pragma unroll
        for (int nt = 0; nt < 4; ++nt) {
            const int colx = col0 + wn * 64 + nt * 16 + cl;
            bv[nt] = b[colx];
            wv2[nt] = Wo[colx];
        }
        #pragma unroll
        for (int mt = 0; mt < 4; ++mt) {
            #pragma unroll
            for (int rr = 0; rr < 4; ++rr) {
                float s = 0.0f;
                #pragma unroll
                for (int nt = 0; nt < 4; ++nt)
                    s += fmaxf(acc[mt][nt][rr] + bv[nt], 0.0f) * wv2[nt];
                s += __shfl_xor(s, 1);
                s += __shfl_xor(s, 2);
                s += __shfl_xor(s, 4);
                s += __shfl_xor(s, 8);
                int row = row0 + wm * 64 + mt * 16 + quad * 4 + rr;
                if (cl == 0 && row < N) atomicAdd(&logit[row], s);
            }
        }
    }
}

// ---------------- layer-2: 128x256-tile 3-buf GEMM + fused head ------------
// C = relu([A0|A1] @ W^T + b); logit[row] += sum_col C[row,col]*Wo[col].
// Fixed shape: A row stride 512 (K0=K1=512, K=1024), W [512][1024].
// 512 thr = 8 waves (2 wr x 4 wc), wave tile 64x64, BK=32, 32 K-tiles.
// LDS: A 3x8KB @ [0,24576) + B 3x16KB @ [24576,73728). 2 blocks/CU.
// Phase t: [vmcnt(3) gate][barrier] RD(buf t%3) STG(t+2 -> buf (t+2)%3)
//          setprio(1) 16 MFMA setprio(0).
// Gate proof: outstanding at gate = stages from ph(t-2) (tile t, 3 instr)
// + ph(t-1) (tile t+1, 3 instr) = 6; vmcnt(3) waits the oldest 3 = tile t.
// Overwrite proof: STG(t+2) targets buf((t+2)%3) = buf((t-1)%3), last read
// in ph(t-1); reads retired before each wave's ph(t-1) MFMA, hence before
// its ph(t) barrier arrival; STG issues after the barrier. Gate BEFORE the
// barrier so the all-waves join publishes each wave's DMA completion.

#define KT3 32   // K-tiles of 32 (K = 1024)

#define STG3(kt) do {                                                          \
    const unsigned short* _p = ((kt) < 16) ? (A0 + ((kt) << 5))                \
                                           : (A1 + (((kt) - 16) << 5));        \
    const int _bf = (kt) % 3;                                                  \
    GLOAD_LDS16(_p + offA, lds + _bf * 8192 + w * 1024);                       \
    GLOAD_LDS16(W + ((kt) << 5) + offB0,                                       \
                lds + 24576 + _bf * 16384 + w * 2048);                         \
    GLOAD_LDS16(W + ((kt) << 5) + offB1,                                       \
                lds + 24576 + _bf * 16384 + w * 2048 + 1024);                  \
} while (0)

#define RD3(bf) do {                                                           \
    _Pragma("unroll")                                                          \
    for (int _m = 0; _m < 4; ++_m)                                             \
        af[_m] = *(const bf16x8*)(lds + (bf) * 8192 + aoff + _m * 1024);       \
    _Pragma("unroll")                                                          \
    for (int _n = 0; _n < 4; ++_n)                                             \
        bq[_n] = *(const bf16x8*)(lds + 24576 + (bf) * 16384 + boff + _n * 1024); \
} while (0)

#define MM16() do {                                                            \
    _Pragma("unroll")                                                          \
    for (int _m = 0; _m < 4; ++_m)                                             \
        _Pragma("unroll")                                                      \
        for (int _n = 0; _n < 4; ++_n)                                         \
            acc[_m][_n] = __builtin_amdgcn_mfma_f32_16x16x32_bf16(             \
                af[_m], bq[_n], acc[_m][_n], 0, 0, 0);                         \
} while (0)

#define PHASE3(t, stage, gatestr) do {                                         \
    __builtin_amdgcn_sched_barrier(0);                                         \
    asm volatile("s_waitcnt " gatestr ::: "memory");                           \
    __builtin_amdgcn_s_barrier();                                              \
    __builtin_amdgcn_sched_barrier(0);                                         \
    RD3((t) % 3);                                                              \
    if (stage) STG3((t) + 2);                                                  \
    __builtin_amdgcn_s_setprio(1);                                             \
    MM16();                                                                    \
    __builtin_amdgcn_s_setprio(0);                                             \
} while (0)

__global__ __launch_bounds__(512, 4) void gemm2_3buf(
    const unsigned short* __restrict__ A0,   // h1b [N,512] bf16
    const unsigned short* __restrict__ A1,   // n2b [N,512] bf16
    const unsigned short* __restrict__ W,    // W2b [512,1024] bf16
    const float* __restrict__ b,             // b2 [512]
    const float* __restrict__ Wo,            // [512]
    float* __restrict__ logit,               // [N]
    int N)
{
    __shared__ char lds[73728];              // A 3x8K | B 3x16K

    // bijective XCD swizzle (m204): contiguous virt chunk per XCD; the two
    // col-siblings of a row-tile are consecutive virt -> same XCD (A L2 reuse)
    const int nwg  = ((N + 127) >> 7) * 2;
    const int orig = blockIdx.x;
    const int xcd = orig & 7, lnum = orig >> 3;
    const int q = nwg >> 3, r = nwg & 7;
    const int virt = (xcd < r ? xcd * (q + 1) : r * (q + 1) + (xcd - r) * q) + lnum;
    const int row0 = (virt >> 1) << 7;       // 128-row tile
    const int col0 = (virt & 1) << 8;        // 256-col tile

    const int tid = threadIdx.x;
    const int w = tid >> 6, l = tid & 63;
    const int wr = w >> 2, wc = w & 3;       // 2x4 wave grid, 64x64 wave tile
    const int cl = l & 15, quad = l >> 4;

    // ---- staging addresses (inverse-swizzled global source; linear dest) ----
    // A dest: row = w*16 + (l>>2), slot = l&3. B dest (instr i): row =
    // w*32 + i*16 + (l>>2). Both have (row>>1)&3 == (l>>3)&3, so logical
    // col slot = (l&3) ^ ((l>>3)&3)  -> c_log elements = 8 * that.
    const int c_log = (((l & 3) ^ ((l >> 3) & 3))) * 8;
    int ra = row0 + w * 16 + (l >> 2);
    if (ra > N - 1) ra = N - 1;              // clamp; epilogue guards row<N
    const size_t offA  = (size_t)ra * 512 + c_log;
    const size_t offB0 = (size_t)(col0 + w * 32 + (l >> 2)) * 1024 + c_log;
    const size_t offB1 = (size_t)(col0 + w * 32 + 16 + (l >> 2)) * 1024 + c_log;

    // ---- ds_read: phys = logical ^ (((row>>1)&3)<<4); (row>>1)&3 = (cl>>1)&3
    const int swz  = ((cl >> 1) & 3) << 4;
    const int aoff = (((wr * 64 + cl) * 64) + quad * 16) ^ swz;   // + mt*1024
    const int boff = (((wc * 64 + cl) * 64) + quad * 16) ^ swz;   // + nt*1024

    f32x4 acc[4][4];
    #pragma unroll
    for (int mt = 0; mt < 4; ++mt)
        #pragma unroll
        for (int nt = 0; nt < 4; ++nt)
            acc[mt][nt] = (f32x4){0.f, 0.f, 0.f, 0.f};

    bf16x8 af[4], bq[4];

    // ---- prologue: stage tiles 0,1 (6 instr/wave) ----
    STG3(0); STG3(1);

    #pragma unroll
    for (int t = 0; t < 30; ++t)
        PHASE3(t, 1, "vmcnt(3)");
    PHASE3(30, 0, "vmcnt(3)");
    PHASE3(31, 0, "vmcnt(0)");

    // ---- epilogue: fused ReLU + Wo dot + atomic row add ----
    float bv[4], wv[4];
    #pragma unroll
    for (int nt = 0; nt < 4; ++nt) {
        const int colx = col0 + wc * 64 + nt * 16 + cl;
        bv[nt] = b[colx];
        wv[nt] = Wo[colx];
    }
    #pragma unroll
    for (int mt = 0; mt < 4; ++mt) {
        #pragma unroll
        for (int rr = 0; rr < 4; ++rr) {
            float s = 0.0f;
            #pragma unroll
            for (int nt = 0; nt < 4; ++nt)
                s += fmaxf(acc[mt][nt][rr] + bv[nt], 0.0f) * wv[nt];
            s += __shfl_xor(s, 1);
            s += __shfl_xor(s, 2);
            s += __shfl_xor(s, 4);
            s += __shfl_xor(s, 8);
            const int row = row0 + wr * 64 + mt * 16 + quad * 4 + rr;
            if (cl == 0 && row < N) atomicAdd(&logit[row], s);
        }
    }
}

__global__ void head_kernel(const float* __restrict__ logit, const float* __restrict__ bo,
                            float* __restrict__ out, int N) {
    int i = blockIdx.x * 256 + threadIdx.x;
    if (i < N) out[i] = 1.0f / (1.0f + expf(-(logit[i] + bo[0])));
}

extern "C" void kernel_launch(void* const* d_in, const int* in_sizes, int n_in,
                              void* d_out, int out_size, void* d_ws, size_t ws_size,
                              hipStream_t stream) {
    const float* x  = (const float*)d_in[0];
    const int*   ei = (const int*)d_in[1];
    const float* W1 = (const float*)d_in[2];
    const float* b1 = (const float*)d_in[3];
    const float* W2 = (const float*)d_in[4];
    const float* b2 = (const float*)d_in[5];
    const float* Wo = (const float*)d_in[6];
    const float* bo = (const float*)d_in[7];
    float* out = (float*)d_out;

    const int N = in_sizes[0] / 128;   // 50000
    const int E = in_sizes[1] / 2;     // 400000
    const int* src = ei;
    const int* dst = ei + E;

    char* ws = (char*)d_ws;
    size_t off = 0;
    auto alloc = [&](size_t bytes) {
        void* p = ws + off;
        off += (bytes + 255) & ~(size_t)255;
        return p;
    };
    int* deg      = (int*)alloc((size_t)N * 4);
    int* rowstart = (int*)alloc((size_t)(N + 1) * 4);
    int* cursor   = (int*)alloc((size_t)N * 4);
    int* partial  = (int*)alloc((size_t)64 * 4);
    int* ebuf     = (int*)alloc((size_t)E * 4);
    float* logit  = (float*)alloc((size_t)N * 4);
    unsigned short* xb  = (unsigned short*)alloc((size_t)N * 128 * 2);
    unsigned short* W1b = (unsigned short*)alloc((size_t)512 * 256 * 2);
    unsigned short* W2b = (unsigned short*)alloc((size_t)512 * 1024 * 2);
    unsigned short* n1b = (unsigned short*)alloc((size_t)N * 128 * 2);
    unsigned short* h1b = (unsigned short*)alloc((size_t)N * 512 * 2);
    unsigned short* n2b = (unsigned short*)alloc((size_t)N * 512 * 2);
    (void)ws_size; (void)n_in; (void)out_size;

    hipMemsetAsync(deg,   0, (size_t)N * 4, stream);
    hipMemsetAsync(logit, 0, (size_t)N * 4, stream);

    // fused: cvt x/W1/W2 -> bf16  +  deg histogram (independent DAG roots)
    const int na4 = N * 128 / 4, nb4 = 512 * 256 / 4, nc4 = 512 * 1024 / 4;
    const int cvt_blocks  = ceil_div(na4 + nb4 + nc4, 256);
    const int hist_blocks = ceil_div(E, 256);
    cvt3_hist_kernel<<<cvt_blocks + hist_blocks, 256, 0, stream>>>(
        x, xb, na4, W1, W1b, nb4, W2, W2b, nc4, dst, deg, E, cvt_blocks);

    // CSR build (hierarchical scan)
    const int P = ceil_div(N, 1024);   // 49
    chunk_reduce<<<P, 256, 0, stream>>>(deg, partial, N);
    partial_scan<<<1, 64, 0, stream>>>(partial, rowstart + N, P);
    chunk_scan<<<P, 256, 0, stream>>>(deg, partial, rowstart, cursor, N);
    bucket_kernel<<<ceil_div(E, 256), 256, 0, stream>>>(src, dst, cursor, ebuf, E);

    // layer 1: 128^2-tile kernel (K=256, small) — XCD-swizzled 1D grid
    const int nrow = ceil_div(N, 128);              // 391
    const int gblocks = ceil_div(nrow, 8) * 8 * 4;  // 1568
    gather_mean_128<<<ceil_div(N * 64, 256), 256, 0, stream>>>(rowstart, ebuf,
                                                               (const unsigned*)xb, (unsigned*)n1b, N);
    gemm_mfma<<<gblocks, 256, 0, stream>>>(xb, n1b, W1b, b1, h1b, nullptr, nullptr,
                                           N, 128, 128, 512, 0);

    // layer 2 + fused head: 128x256-tile 3-buf kernel, 2 blocks/CU
    gather_mean_512<<<ceil_div(N * 64, 256), 256, 0, stream>>>(rowstart, ebuf, h1b, n2b, N);
    const int g2 = ceil_div(N, 128) * 2;            // 782 blocks
    gemm2_3buf<<<g2, 512, 0, stream>>>(h1b, n2b, W2b, b2, Wo, logit, N);

    head_kernel<<<ceil_div(N, 256), 256, 0, stream>>>(logit, bo, out, N);
}

// Round 5
// 330.615 us; speedup vs baseline: 1.0600x; 1.0149x over previous
//
#include <hip/hip_runtime.h>
#include <math.h>

// ---------------------------------------------------------------------------
// GraphSAGE fraud detector. CSR-gather aggregation + bf16 MFMA GEMMs.
// R21: layer-2 GEMM -> B-in-registers. R20 post-mortem: 2 blocks/CU landed
// (occ 29%, VGPR 64) but time flat at 69us -> the saturated pipe is LDS BW
// (176KB/phase-step/CU vs 620cy MFMA). Fix: W2 is repacked at cvt time into
// MFMA-fragment-linear order; each wave loads its per-phase B fragment as
// 4 contiguous-1KB global_load_dwordx4 directly to registers (L2-hot, L1
// absorbs the x2 intra-block duplicate). LDS holds A only (3 x 8KB = 24KB);
// per-phase LDS traffic 88KB -> 40KB, below the 25us MFMA floor.
// Pipelining: A via global_load_lds 2-phase lead, gate vmcnt(5) (queue at
// top of phase t is <= [A(t),B(t-1)x4,A(t+1),B(t)x4] -> drains A(t));
// B(t+1) loads issue after MFMA(t) (1-phase lead >> L2 latency); compiler
// counted waits cover the bq->MFMA dep. A swizzle/staging = R20 (0 confl).
// Wf layout: elem off = ((((t*8+g)*4+nt)*4+quad)*16+cl)*8+j,
//   g=c>>6, nt=(c>>4)&3, cl=c&15, t=k>>5, quad=(k>>3)&3, j=k&7.
// MFMA 16x16x32 bf16: A-frag A[m=lane&15][k=quad*8+j]; C/D col=lane&15,
// row=quad*4+reg (m89/m97-verified layouts).
// ---------------------------------------------------------------------------

typedef __attribute__((ext_vector_type(8))) short bf16x8;   // 8 bf16, 4 VGPRs
typedef __attribute__((ext_vector_type(4))) float f32x4;

static inline int ceil_div(int a, int b) { return (a + b - 1) / b; }

__device__ inline float bf2f_lo(unsigned u) { return __builtin_bit_cast(float, u << 16); }
__device__ inline float bf2f_hi(unsigned u) { return __builtin_bit_cast(float, u & 0xffff0000u); }
__device__ inline unsigned f2bf(float f) {   // RNE round to bf16, bits in low 16
    unsigned u = __builtin_bit_cast(unsigned, f);
    u += 0x7fffu + ((u >> 16) & 1u);
    return u >> 16;
}

// async global->LDS, 16 B per lane; LDS dest = wave-uniform base + lane*16
#define GLOAD_LDS16(gp, lp)                                                   \
    __builtin_amdgcn_global_load_lds(                                         \
        (__attribute__((address_space(1))) void*)(gp),                        \
        (__attribute__((address_space(3))) void*)(lp), 16, 0, 0)

// ---------------- fused cvt(x,W1,W2) + deg histogram ----------------
// W2 branch packs into the Wf fragment-linear layout (see header).

__global__ void cvt3_hist_kernel(const float* __restrict__ a, unsigned short* __restrict__ ao, int na4,
                                 const float* __restrict__ b, unsigned short* __restrict__ bo, int nb4,
                                 const float* __restrict__ c, unsigned short* __restrict__ co, int nc4,
                                 const int* __restrict__ dst, int* __restrict__ deg, int E,
                                 int cvt_blocks) {
    if ((int)blockIdx.x < cvt_blocks) {
        int i = blockIdx.x * 256 + threadIdx.x;
        if (i < na4 + nb4) {
            const float* in; unsigned short* out; int k;
            if (i < na4) { in = a; out = ao; k = i; }
            else         { in = b; out = bo; k = i - na4; }
            float4 v = ((const float4*)in)[k];
            ushort4 o;
            o.x = (unsigned short)f2bf(v.x);
            o.y = (unsigned short)f2bf(v.y);
            o.z = (unsigned short)f2bf(v.z);
            o.w = (unsigned short)f2bf(v.w);
            ((ushort4*)out)[k] = o;
        } else if (i < na4 + nb4 + nc4) {
            int kk = i - na4 - nb4;            // float4 idx into W2 [512][1024]
            float4 v = ((const float4*)c)[kk];
            ushort4 o;
            o.x = (unsigned short)f2bf(v.x);
            o.y = (unsigned short)f2bf(v.y);
            o.z = (unsigned short)f2bf(v.z);
            o.w = (unsigned short)f2bf(v.w);
            const int cc = kk >> 8;            // row (col of GEMM-B), 0..511
            const int kq = kk & 255;           // float4 within row
            const int t    = kq >> 3;          // k-tile of 32
            const int quad = (kq >> 1) & 3;
            const int j0   = (kq & 1) * 4;
            const int g  = cc >> 6, nt = (cc >> 4) & 3, cl = cc & 15;
            const size_t off =
                ((((size_t)(t * 8 + g) * 4 + nt) * 4 + quad) * 16 + cl) * 8 + j0;
            *(ushort4*)(co + off) = o;
        }
    } else {
        int e = (blockIdx.x - cvt_blocks) * 256 + threadIdx.x;
        if (e < E) atomicAdd(&deg[dst[e]], 1);
    }
}

// ---------------- CSR build ----------------

// per-1024-chunk sums
__global__ __launch_bounds__(256) void chunk_reduce(const int* __restrict__ deg,
                                                    int* __restrict__ partial, int N) {
    int base = blockIdx.x * 1024;
    int s = 0;
    for (int i = threadIdx.x; i < 1024; i += 256) {
        int idx = base + i;
        if (idx < N) s += deg[idx];
    }
    #pragma unroll
    for (int off = 32; off; off >>= 1) s += __shfl_down(s, off);
    __shared__ int ws[4];
    if ((threadIdx.x & 63) == 0) ws[threadIdx.x >> 6] = s;
    __syncthreads();
    if (threadIdx.x == 0) partial[blockIdx.x] = ws[0] + ws[1] + ws[2] + ws[3];
}

// exclusive scan of P<=64 partials (one wave); writes rowstart[N]=total
__global__ void partial_scan(int* __restrict__ partial, int* __restrict__ rowstartN, int P) {
    int lane = threadIdx.x;
    int v = (lane < P) ? partial[lane] : 0;
    int incl = v;
    #pragma unroll
    for (int off = 1; off < 64; off <<= 1) {
        int t = __shfl_up(incl, off);
        if (lane >= off) incl += t;
    }
    if (lane < P) partial[lane] = incl - v;
    if (lane == 63) *rowstartN = incl;
}

// per-chunk exclusive scan + global offset; writes rowstart and cursor
__global__ __launch_bounds__(256) void chunk_scan(const int* __restrict__ deg,
                                                  const int* __restrict__ partial,
                                                  int* __restrict__ rowstart,
                                                  int* __restrict__ cursor, int N) {
    int base = blockIdx.x * 1024 + threadIdx.x * 4;
    int v[4];
    #pragma unroll
    for (int j = 0; j < 4; ++j) {
        int i = base + j;
        v[j] = (i < N) ? deg[i] : 0;
    }
    int mysum = v[0] + v[1] + v[2] + v[3];
    int incl = mysum;
    int lane = threadIdx.x & 63, wave = threadIdx.x >> 6;
    #pragma unroll
    for (int off = 1; off < 64; off <<= 1) {
        int t = __shfl_up(incl, off);
        if (lane >= off) incl += t;
    }
    __shared__ int ws[4];
    if (lane == 63) ws[wave] = incl;
    __syncthreads();
    int run = partial[blockIdx.x] + incl - mysum;
    for (int w = 0; w < wave; ++w) run += ws[w];
    #pragma unroll
    for (int j = 0; j < 4; ++j) {
        int i = base + j;
        if (i < N) { rowstart[i] = run; cursor[i] = run; }
        run += v[j];
    }
}

__global__ void bucket_kernel(const int* __restrict__ src, const int* __restrict__ dst,
                              int* __restrict__ cursor, int* __restrict__ ebuf, int E) {
    int e = blockIdx.x * 256 + threadIdx.x;
    if (e < E) {
        int pos = atomicAdd(&cursor[dst[e]], 1);
        ebuf[pos] = src[e];
    }
}

// ---------------- gather means ----------------

// one wave per dst row; bf16 xb [N,128] -> bf16 mean [N,128]; fp32 accum
__global__ void gather_mean_128(const int* __restrict__ rowstart, const int* __restrict__ ebuf,
                                const unsigned* __restrict__ featb, unsigned* __restrict__ outb, int N) {
    int w = (blockIdx.x * blockDim.x + threadIdx.x) >> 6;
    int lane = threadIdx.x & 63;
    if (w >= N) return;
    int e0 = rowstart[w], e1 = rowstart[w + 1];
    float ax = 0.0f, ay = 0.0f;
    int i = e0;
    for (; i + 8 <= e1; i += 8) {           // 8-edge unroll for MLP
        unsigned v0 = featb[(size_t)ebuf[i]     * 64 + lane];
        unsigned v1 = featb[(size_t)ebuf[i + 1] * 64 + lane];
        unsigned v2 = featb[(size_t)ebuf[i + 2] * 64 + lane];
        unsigned v3 = featb[(size_t)ebuf[i + 3] * 64 + lane];
        unsigned v4 = featb[(size_t)ebuf[i + 4] * 64 + lane];
        unsigned v5 = featb[(size_t)ebuf[i + 5] * 64 + lane];
        unsigned v6 = featb[(size_t)ebuf[i + 6] * 64 + lane];
        unsigned v7 = featb[(size_t)ebuf[i + 7] * 64 + lane];
        ax += bf2f_lo(v0) + bf2f_lo(v1) + bf2f_lo(v2) + bf2f_lo(v3)
            + bf2f_lo(v4) + bf2f_lo(v5) + bf2f_lo(v6) + bf2f_lo(v7);
        ay += bf2f_hi(v0) + bf2f_hi(v1) + bf2f_hi(v2) + bf2f_hi(v3)
            + bf2f_hi(v4) + bf2f_hi(v5) + bf2f_hi(v6) + bf2f_hi(v7);
    }
    for (; i < e1; ++i) {
        unsigned v = featb[(size_t)ebuf[i] * 64 + lane];
        ax += bf2f_lo(v); ay += bf2f_hi(v);
    }
    float inv = 1.0f / fmaxf((float)(e1 - e0), 1.0f);
    outb[(size_t)w * 64 + lane] = f2bf(ax * inv) | (f2bf(ay * inv) << 16);
}

// one wave per dst row; bf16 feat [N,512] -> bf16 mean [N,512]; fp32 accum
__global__ void gather_mean_512(const int* __restrict__ rowstart, const int* __restrict__ ebuf,
                                const unsigned short* __restrict__ featb,
                                unsigned short* __restrict__ outb, int N) {
    int w = (blockIdx.x * blockDim.x + threadIdx.x) >> 6;
    int lane = threadIdx.x & 63;
    if (w >= N) return;
    int e0 = rowstart[w], e1 = rowstart[w + 1];
    float a[8] = {0, 0, 0, 0, 0, 0, 0, 0};
    const uint4* base = (const uint4*)featb;     // 512 bf16/row = 64 uint4/row
    int i = e0;
    for (; i + 8 <= e1; i += 8) {           // 8-edge unroll for MLP
        uint4 v0 = base[(size_t)ebuf[i]     * 64 + lane];
        uint4 v1 = base[(size_t)ebuf[i + 1] * 64 + lane];
        uint4 v2 = base[(size_t)ebuf[i + 2] * 64 + lane];
        uint4 v3 = base[(size_t)ebuf[i + 3] * 64 + lane];
        uint4 v4 = base[(size_t)ebuf[i + 4] * 64 + lane];
        uint4 v5 = base[(size_t)ebuf[i + 5] * 64 + lane];
        uint4 v6 = base[(size_t)ebuf[i + 6] * 64 + lane];
        uint4 v7 = base[(size_t)ebuf[i + 7] * 64 + lane];
        a[0] += bf2f_lo(v0.x) + bf2f_lo(v1.x) + bf2f_lo(v2.x) + bf2f_lo(v3.x)
              + bf2f_lo(v4.x) + bf2f_lo(v5.x) + bf2f_lo(v6.x) + bf2f_lo(v7.x);
        a[1] += bf2f_hi(v0.x) + bf2f_hi(v1.x) + bf2f_hi(v2.x) + bf2f_hi(v3.x)
              + bf2f_hi(v4.x) + bf2f_hi(v5.x) + bf2f_hi(v6.x) + bf2f_hi(v7.x);
        a[2] += bf2f_lo(v0.y) + bf2f_lo(v1.y) + bf2f_lo(v2.y) + bf2f_lo(v3.y)
              + bf2f_lo(v4.y) + bf2f_lo(v5.y) + bf2f_lo(v6.y) + bf2f_lo(v7.y);
        a[3] += bf2f_hi(v0.y) + bf2f_hi(v1.y) + bf2f_hi(v2.y) + bf2f_hi(v3.y)
              + bf2f_hi(v4.y) + bf2f_hi(v5.y) + bf2f_hi(v6.y) + bf2f_hi(v7.y);
        a[4] += bf2f_lo(v0.z) + bf2f_lo(v1.z) + bf2f_lo(v2.z) + bf2f_lo(v3.z)
              + bf2f_lo(v4.z) + bf2f_lo(v5.z) + bf2f_lo(v6.z) + bf2f_lo(v7.z);
        a[5] += bf2f_hi(v0.z) + bf2f_hi(v1.z) + bf2f_hi(v2.z) + bf2f_hi(v3.z)
              + bf2f_hi(v4.z) + bf2f_hi(v5.z) + bf2f_hi(v6.z) + bf2f_hi(v7.z);
        a[6] += bf2f_lo(v0.w) + bf2f_lo(v1.w) + bf2f_lo(v2.w) + bf2f_lo(v3.w)
              + bf2f_lo(v4.w) + bf2f_lo(v5.w) + bf2f_lo(v6.w) + bf2f_lo(v7.w);
        a[7] += bf2f_hi(v0.w) + bf2f_hi(v1.w) + bf2f_hi(v2.w) + bf2f_hi(v3.w)
              + bf2f_hi(v4.w) + bf2f_hi(v5.w) + bf2f_hi(v6.w) + bf2f_hi(v7.w);
    }
    for (; i < e1; ++i) {
        uint4 v = base[(size_t)ebuf[i] * 64 + lane];
        a[0] += bf2f_lo(v.x); a[1] += bf2f_hi(v.x);
        a[2] += bf2f_lo(v.y); a[3] += bf2f_hi(v.y);
        a[4] += bf2f_lo(v.z); a[5] += bf2f_hi(v.z);
        a[6] += bf2f_lo(v.w); a[7] += bf2f_hi(v.w);
    }
    float inv = 1.0f / fmaxf((float)(e1 - e0), 1.0f);
    uint4 o;
    o.x = f2bf(a[0] * inv) | (f2bf(a[1] * inv) << 16);
    o.y = f2bf(a[2] * inv) | (f2bf(a[3] * inv) << 16);
    o.z = f2bf(a[4] * inv) | (f2bf(a[5] * inv) << 16);
    o.w = f2bf(a[6] * inv) | (f2bf(a[7] * inv) << 16);
    ((uint4*)outb)[(size_t)w * 64 + lane] = o;
}

// ---------------- bf16 MFMA GEMM (R12-exact: BK=32, XCD swizzle) -----------
// Retained for layer 1 (K=256).
__global__ __launch_bounds__(256) void gemm_mfma(
    const unsigned short* __restrict__ A0,   // [N, K0] bf16
    const unsigned short* __restrict__ A1,   // [N, K1] bf16, K1 == K0
    const unsigned short* __restrict__ W,    // [C, K0+K1] bf16 row-major
    const float* __restrict__ b,             // [C] fp32
    unsigned short* __restrict__ outb,       // [N, C] bf16 (mode 0)
    const float* __restrict__ Wo,            // [C] fp32    (mode 1)
    float* __restrict__ logit,               // [N] fp32    (mode 1)
    int N, int K0, int K1, int C, int mode)
{
    // --- XCD-aware decode ---
    const int nrow = (N + 127) >> 7;
    const int id   = blockIdx.x;
    const int rowb = ((id >> 5) << 3) + (id & 7);   // rslot*8 + xcd
    const int colb = (id >> 3) & 3;
    if (rowb >= nrow) return;

    const int K = K0 + K1;
    const int S = K0;               // row stride of both A0 and A1
    __shared__ short As[2][4096];   // [128][32] per buffer, 8 KB
    __shared__ short Bs[2][4096];

    const int tid  = threadIdx.x;
    const int lane = tid & 63;
    const int wave = tid >> 6;
    const int wm = wave & 1, wn = wave >> 1;
    const int cl = lane & 15, quad = lane >> 4;
    const int row0 = rowb * 128;
    const int col0 = colb * 128;

    // staging: lane = 4r+j; wave w, load i covers tile rows w*32+i*16 .. +16
    const int r = lane >> 2;        // 0..15
    const int j = lane & 3;         // 16B chunk within the row's 64B K-slice
    const int trow0 = wave * 32 + r;
    const int trow1 = trow0 + 16;
    // clamp OOB tile rows to N-1 (loaded garbage discarded by epilogue guard)
    const int ar0 = (row0 + trow0 < N) ? row0 + trow0 : N - 1;
    const int ar1 = (row0 + trow1 < N) ? row0 + trow1 : N - 1;
    const size_t aoff0 = (size_t)ar0 * S + j * 8;
    const size_t aoff1 = (size_t)ar1 * S + j * 8;
    const size_t boff0 = (size_t)(col0 + trow0) * K + j * 8;
    const size_t boff1 = (size_t)(col0 + trow1) * K + j * 8;
    const int lds0 = (wave * 32) * 32;        // shorts; wave-uniform
    const int lds1 = (wave * 32 + 16) * 32;

    f32x4 acc[4][4];
    #pragma unroll
    for (int mt = 0; mt < 4; ++mt)
        #pragma unroll
        for (int nt = 0; nt < 4; ++nt)
            acc[mt][nt] = (f32x4){0.f, 0.f, 0.f, 0.f};

    // prologue: DMA tile 0 into buffer 0
    GLOAD_LDS16(A0 + aoff0, &As[0][lds0]);
    GLOAD_LDS16(A0 + aoff1, &As[0][lds1]);
    GLOAD_LDS16(W  + boff0, &Bs[0][lds0]);
    GLOAD_LDS16(W  + boff1, &Bs[0][lds1]);

    const int iters = K >> 5;
    for (int i = 0; i < iters; ++i) {
        const int cur = i & 1;
        // barrier drains tile i's DMA (vmcnt0) and fences tile i-1 frag reads
        __syncthreads();
        if (i + 1 < iters) {
            const int kn = (i + 1) << 5;
            const unsigned short* Ab = (kn < K0) ? (A0 + kn) : (A1 + (kn - K0));
            const unsigned short* Wb = W + kn;
            const int nb = cur ^ 1;
            GLOAD_LDS16(Ab + aoff0, &As[nb][lds0]);
            GLOAD_LDS16(Ab + aoff1, &As[nb][lds1]);
            GLOAD_LDS16(Wb + boff0, &Bs[nb][lds0]);
            GLOAD_LDS16(Wb + boff1, &Bs[nb][lds1]);
        }

        bf16x8 af[4], bfr[4];
        #pragma unroll
        for (int mt = 0; mt < 4; ++mt)
            af[mt] = *(const bf16x8*)&As[cur][(wm * 64 + mt * 16 + cl) * 32 + quad * 8];
        #pragma unroll
        for (int nt = 0; nt < 4; ++nt)
            bfr[nt] = *(const bf16x8*)&Bs[cur][(wn * 64 + nt * 16 + cl) * 32 + quad * 8];

        #pragma unroll
        for (int mt = 0; mt < 4; ++mt)
            #pragma unroll
            for (int nt = 0; nt < 4; ++nt)
                acc[mt][nt] = __builtin_amdgcn_mfma_f32_16x16x32_bf16(
                    af[mt], bfr[nt], acc[mt][nt], 0, 0, 0);
    }

    if (mode == 0) {
        #pragma unroll
        for (int nt = 0; nt < 4; ++nt) {
            const int colx = col0 + wn * 64 + nt * 16 + cl;
            const float bb = b[colx];
            #pragma unroll
            for (int mt = 0; mt < 4; ++mt) {
                #pragma unroll
                for (int rr = 0; rr < 4; ++rr) {
                    int row = row0 + wm * 64 + mt * 16 + quad * 4 + rr;
                    if (row < N)
                        outb[(size_t)row * C + colx] =
                            (unsigned short)f2bf(fmaxf(acc[mt][nt][rr] + bb, 0.0f));
                }
            }
        }
    } else {
        float bv[4], wv2[4];
        #pragma unroll
        for (int nt = 0; nt < 4; ++nt) {
            const int colx = col0 + wn * 64 + nt * 16 + cl;
            bv[nt] = b[colx];
            wv2[nt] = Wo[colx];
        }
        #pragma unroll
        for (int mt = 0; mt < 4; ++mt) {
            #pragma unroll
            for (int rr = 0; rr < 4; ++rr) {
                float s = 0.0f;
                #pragma unroll
                for (int nt = 0; nt < 4; ++nt)
                    s += fmaxf(acc[mt][nt][rr] + bv[nt], 0.0f) * wv2[nt];
                s += __shfl_xor(s, 1);
                s += __shfl_xor(s, 2);
                s += __shfl_xor(s, 4);
                s += __shfl_xor(s, 8);
                int row = row0 + wm * 64 + mt * 16 + quad * 4 + rr;
                if (cl == 0 && row < N) atomicAdd(&logit[row], s);
            }
        }
    }
}

// ---------------- layer-2: 128x256 tile, A-in-LDS + B-in-regs --------------
// C = relu([A0|A1] @ W^T + b); logit[row] += sum_col C[row,col]*Wo[col].
// W = Wf fragment-packed (see cvt). 512 thr = 8 waves (2 wr x 4 wc),
// wave tile 64x64, BK=32, 32 K-tiles. LDS: A only, 3 x 8KB. 2+ blocks/CU.
// Phase t: [vmcnt(5)][barrier] RD_A(t%3) STG_A(t+2) MFMA(t; bq=B(t))
//          LDB(t+1 -> bq).
// Gate proof: VMEM queue at top of phase t (oldest first):
//   A(t), B(t-1)x4, A(t+1), B(t)x4  -> vmcnt(5) drains A(t)+B(t-1).
// bq->MFMA dep: compiler-counted vmcnt (one-phase lead >> L2 latency; W hot).
// A overwrite WAR: STG_A(t+2) hits buf((t-1)%3); phase t-1 reads retired
// before each wave's MFMA(t-1) (compiler lgkmcnt) hence before its phase-t
// barrier arrival; STG issues after that barrier.

#define STGA(kt) do {                                                          \
    const unsigned short* _p = ((kt) < 16) ? (A0 + ((kt) << 5))                \
                                           : (A1 + (((kt) - 16) << 5));        \
    GLOAD_LDS16(_p + offA, lds + ((kt) % 3) * 8192 + w * 1024);                \
} while (0)

#define LDB(kt) do {                                                           \
    _Pragma("unroll")                                                          \
    for (int _n = 0; _n < 4; ++_n)                                             \
        bq[_n] = *(const bf16x8*)(W +                                          \
            (((size_t)(kt) * 8 + gB) * 4 + _n) * 512 + l * 8);                 \
} while (0)

#define RDA(bf) do {                                                           \
    _Pragma("unroll")                                                          \
    for (int _m = 0; _m < 4; ++_m)                                             \
        af[_m] = *(const bf16x8*)(lds + (bf) * 8192 + aoff + _m * 1024);       \
} while (0)

#define MM16B() do {                                                           \
    _Pragma("unroll")                                                          \
    for (int _m = 0; _m < 4; ++_m)                                             \
        _Pragma("unroll")                                                      \
        for (int _n = 0; _n < 4; ++_n)                                         \
            acc[_m][_n] = __builtin_amdgcn_mfma_f32_16x16x32_bf16(             \
                af[_m], bq[_n], acc[_m][_n], 0, 0, 0);                         \
} while (0)

#define PHASE4(t, stage) do {                                                  \
    __builtin_amdgcn_sched_barrier(0);                                         \
    asm volatile("s_waitcnt vmcnt(5)" ::: "memory");                           \
    __builtin_amdgcn_s_barrier();                                              \
    __builtin_amdgcn_sched_barrier(0);                                         \
    RDA((t) % 3);                                                              \
    if (stage) STGA((t) + 2);                                                  \
    __builtin_amdgcn_s_setprio(1);                                             \
    MM16B();                                                                   \
    __builtin_amdgcn_s_setprio(0);                                             \
    if ((t) + 1 < 32) LDB((t) + 1);                                            \
} while (0)

__global__ __launch_bounds__(512, 4) void gemm2_breg(
    const unsigned short* __restrict__ A0,   // h1b [N,512] bf16
    const unsigned short* __restrict__ A1,   // n2b [N,512] bf16
    const unsigned short* __restrict__ W,    // Wf fragment-packed [512*1024]
    const float* __restrict__ b,             // b2 [512]
    const float* __restrict__ Wo,            // [512]
    float* __restrict__ logit,               // [N]
    int N)
{
    __shared__ char lds[24576];              // A: 3 x 8KB

    // bijective XCD swizzle (m204): contiguous virt chunk per XCD; the two
    // col-siblings of a row-tile are consecutive virt -> same XCD (A L2 reuse)
    const int nwg  = ((N + 127) >> 7) * 2;
    const int orig = blockIdx.x;
    const int xcd = orig & 7, lnum = orig >> 3;
    const int q = nwg >> 3, r = nwg & 7;
    const int virt = (xcd < r ? xcd * (q + 1) : r * (q + 1) + (xcd - r) * q) + lnum;
    const int row0 = (virt >> 1) << 7;       // 128-row tile
    const int col0 = (virt & 1) << 8;        // 256-col tile

    const int tid = threadIdx.x;
    const int w = tid >> 6, l = tid & 63;
    const int wr = w >> 2, wc = w & 3;       // 2x4 wave grid, 64x64 wave tile
    const int cl = l & 15, quad = l >> 4;
    const int gB = (col0 >> 6) + wc;         // 64-col group for B frags

    // ---- A staging (inverse-swizzled global source; linear LDS dest) ----
    // dest: row = w*16 + (l>>2), slot = l&3; (row>>1)&3 == (l>>3)&3 ->
    // logical col slot = (l&3) ^ ((l>>3)&3); c_log elements = 8 * that.
    const int c_log = (((l & 3) ^ ((l >> 3) & 3))) * 8;
    int ra = row0 + w * 16 + (l >> 2);
    if (ra > N - 1) ra = N - 1;              // clamp; epilogue guards row<N
    const size_t offA = (size_t)ra * 512 + c_log;

    // ---- A ds_read: phys = logical ^ (((row>>1)&3)<<4); (row>>1)&3=(cl>>1)&3
    const int swz  = ((cl >> 1) & 3) << 4;
    const int aoff = (((wr * 64 + cl) * 64) + quad * 16) ^ swz;   // + mt*1024

    f32x4 acc[4][4];
    #pragma unroll
    for (int mt = 0; mt < 4; ++mt)
        #pragma unroll
        for (int nt = 0; nt < 4; ++nt)
            acc[mt][nt] = (f32x4){0.f, 0.f, 0.f, 0.f};

    bf16x8 af[4], bq[4];

    // ---- prologue: stage A tiles 0,1; load B(0) ----
    STGA(0); STGA(1);
    LDB(0);

    #pragma unroll
    for (int t = 0; t < 30; ++t)
        PHASE4(t, 1);
    PHASE4(30, 0);
    PHASE4(31, 0);
    asm volatile("s_waitcnt vmcnt(0)" ::: "memory");   // drain tail

    // ---- epilogue: fused ReLU + Wo dot + atomic row add ----
    float bv[4], wv[4];
    #pragma unroll
    for (int nt = 0; nt < 4; ++nt) {
        const int colx = col0 + wc * 64 + nt * 16 + cl;
        bv[nt] = b[colx];
        wv[nt] = Wo[colx];
    }
    #pragma unroll
    for (int mt = 0; mt < 4; ++mt) {
        #pragma unroll
        for (int rr = 0; rr < 4; ++rr) {
            float s = 0.0f;
            #pragma unroll
            for (int nt = 0; nt < 4; ++nt)
                s += fmaxf(acc[mt][nt][rr] + bv[nt], 0.0f) * wv[nt];
            s += __shfl_xor(s, 1);
            s += __shfl_xor(s, 2);
            s += __shfl_xor(s, 4);
            s += __shfl_xor(s, 8);
            const int row = row0 + wr * 64 + mt * 16 + quad * 4 + rr;
            if (cl == 0 && row < N) atomicAdd(&logit[row], s);
        }
    }
}

__global__ void head_kernel(const float* __restrict__ logit, const float* __restrict__ bo,
                            float* __restrict__ out, int N) {
    int i = blockIdx.x * 256 + threadIdx.x;
    if (i < N) out[i] = 1.0f / (1.0f + expf(-(logit[i] + bo[0])));
}

extern "C" void kernel_launch(void* const* d_in, const int* in_sizes, int n_in,
                              void* d_out, int out_size, void* d_ws, size_t ws_size,
                              hipStream_t stream) {
    const float* x  = (const float*)d_in[0];
    const int*   ei = (const int*)d_in[1];
    const float* W1 = (const float*)d_in[2];
    const float* b1 = (const float*)d_in[3];
    const float* W2 = (const float*)d_in[4];
    const float* b2 = (const float*)d_in[5];
    const float* Wo = (const float*)d_in[6];
    const float* bo = (const float*)d_in[7];
    float* out = (float*)d_out;

    const int N = in_sizes[0] / 128;   // 50000
    const int E = in_sizes[1] / 2;     // 400000
    const int* src = ei;
    const int* dst = ei + E;

    char* ws = (char*)d_ws;
    size_t off = 0;
    auto alloc = [&](size_t bytes) {
        void* p = ws + off;
        off += (bytes + 255) & ~(size_t)255;
        return p;
    };
    int* deg      = (int*)alloc((size_t)N * 4);
    int* rowstart = (int*)alloc((size_t)(N + 1) * 4);
    int* cursor   = (int*)alloc((size_t)N * 4);
    int* partial  = (int*)alloc((size_t)64 * 4);
    int* ebuf     = (int*)alloc((size_t)E * 4);
    float* logit  = (float*)alloc((size_t)N * 4);
    unsigned short* xb  = (unsigned short*)alloc((size_t)N * 128 * 2);
    unsigned short* W1b = (unsigned short*)alloc((size_t)512 * 256 * 2);
    unsigned short* W2b = (unsigned short*)alloc((size_t)512 * 1024 * 2);   // Wf
    unsigned short* n1b = (unsigned short*)alloc((size_t)N * 128 * 2);
    unsigned short* h1b = (unsigned short*)alloc((size_t)N * 512 * 2);
    unsigned short* n2b = (unsigned short*)alloc((size_t)N * 512 * 2);
    (void)ws_size; (void)n_in; (void)out_size;

    hipMemsetAsync(deg,   0, (size_t)N * 4, stream);
    hipMemsetAsync(logit, 0, (size_t)N * 4, stream);

    // fused: cvt x/W1/W2(frag-pack) -> bf16  +  deg histogram
    const int na4 = N * 128 / 4, nb4 = 512 * 256 / 4, nc4 = 512 * 1024 / 4;
    const int cvt_blocks  = ceil_div(na4 + nb4 + nc4, 256);
    const int hist_blocks = ceil_div(E, 256);
    cvt3_hist_kernel<<<cvt_blocks + hist_blocks, 256, 0, stream>>>(
        x, xb, na4, W1, W1b, nb4, W2, W2b, nc4, dst, deg, E, cvt_blocks);

    // CSR build (hierarchical scan)
    const int P = ceil_div(N, 1024);   // 49
    chunk_reduce<<<P, 256, 0, stream>>>(deg, partial, N);
    partial_scan<<<1, 64, 0, stream>>>(partial, rowstart + N, P);
    chunk_scan<<<P, 256, 0, stream>>>(deg, partial, rowstart, cursor, N);
    bucket_kernel<<<ceil_div(E, 256), 256, 0, stream>>>(src, dst, cursor, ebuf, E);

    // layer 1: 128^2-tile kernel (K=256, small) — XCD-swizzled 1D grid
    const int nrow = ceil_div(N, 128);              // 391
    const int gblocks = ceil_div(nrow, 8) * 8 * 4;  // 1568
    gather_mean_128<<<ceil_div(N * 64, 256), 256, 0, stream>>>(rowstart, ebuf,
                                                               (const unsigned*)xb, (unsigned*)n1b, N);
    gemm_mfma<<<gblocks, 256, 0, stream>>>(xb, n1b, W1b, b1, h1b, nullptr, nullptr,
                                           N, 128, 128, 512, 0);

    // layer 2 + fused head: A-in-LDS + B-in-regs kernel
    gather_mean_512<<<ceil_div(N * 64, 256), 256, 0, stream>>>(rowstart, ebuf, h1b, n2b, N);
    const int g2 = ceil_div(N, 128) * 2;            // 782 blocks
    gemm2_breg<<<g2, 512, 0, stream>>>(h1b, n2b, W2b, b2, Wo, logit, N);

    head_kernel<<<ceil_div(N, 256), 256, 0, stream>>>(logit, bo, out, N);
}